// Round 18
// baseline (197.061 us; speedup 1.0000x reference)
//
#include <hip/hip_runtime.h>

// out[n, u*4+s] = sum_{e: dst[e]==n} x[src[e], u] * sh[e, s]
// N=100000, U=32, S=4, E=3200000.
//
// Ledger of lessons:
//  R2: bulk LDS float atomics = ~1 lane/cycle serial floor -> register accum.
//  R4/R5/R7: scattered writes, many streams/block = HBM write amp.
//  R8: few deep-serial blocks (17% occ) lose to 100k shallow blocks.
//  R9/R13: xb/sh are L3-resident across replays; FETCH is L2-fill.
//  R10: NT loads on broadcast/shared streams re-fetch lines.
//  R11/R15/R16: accum: contiguous ranges, 4 nodes/wave, 16 lanes/edge,
//      zero reduction: 99->87->~65us.
//  R12: lane-widening + cross-lane reduction = loss.
//  R13: XCD-swizzle bet on undefined block->XCD mapping: reverted.
//  R17: c1_scatter subchunk LDS-sort + burst write: WRITE 96->~44MB, -8us.
//  R17 counters: c2_sort reads packedA TWICE per sibling (hist + placement)
//      = 40B/edge nominal 128MB.
// R18: c2_sort single-read: stage matching edges UNSORTED in LDS during the
//      hist pass, then place LDS->global sorted (scattered 12B writes inside
//      the 49KB L2-resident window). 24B/edge. Fallback to 2-pass if cnt>SCAP.

#define U_DIM 32
#define US 128

__device__ inline unsigned f2bf(float f) {          // RNE float->bf16 bits
    unsigned u = __float_as_uint(f);
    return (u + 0x7FFF + ((u >> 16) & 1)) >> 16;
}
__device__ inline float bfl(unsigned w) { return __uint_as_float(w << 16); }
__device__ inline float bfh(unsigned w) { return __uint_as_float(w & 0xFFFF0000u); }

__global__ void __launch_bounds__(256) xcvt_kernel(
        const float4* __restrict__ x4, ushort4* __restrict__ xb4, int n4) {
    int i = blockIdx.x * 256 + threadIdx.x;
    if (i < n4) {
        float4 v = x4[i];
        ushort4 r;
        r.x = (unsigned short)f2bf(v.x);
        r.y = (unsigned short)f2bf(v.y);
        r.z = (unsigned short)f2bf(v.z);
        r.w = (unsigned short)f2bf(v.w);
        xb4[i] = r;
    }
}

// =================== PRIMARY PATH ===================
#define C1_LOG 9
#define C1_NPB 512
#define C1_MAXK 256
#define C1_NBLK 256
#define FINE_LOG 7
#define FINE_NPB 128
#define KF_MAX 1024
#define SCAP 5120             // LDS-staged edges per fine bucket (mean 4082)
#define SCH 4096              // c1_scatter subchunk (LDS-sorted burst unit)

// Fine-granularity (128-node) histogram; also per-chunk coarse counts.
__global__ void __launch_bounds__(1024) c1_hist_kernel(
        const int* __restrict__ dst, int* __restrict__ ccount_f,
        int* __restrict__ cnt, int E, int KF, int K1, int EPB) {
    __shared__ int h[KF_MAX];
    for (int b = threadIdx.x; b < KF; b += 1024) h[b] = 0;
    __syncthreads();
    int base = blockIdx.x * EPB;
    int lim = min(EPB, E - base);
    for (int i = threadIdx.x; i < lim; i += 1024)
        atomicAdd(&h[dst[base + i] >> FINE_LOG], 1);
    __syncthreads();
    for (int b = threadIdx.x; b < KF; b += 1024) {
        int c = h[b];
        if (c) atomicAdd(&ccount_f[b], c);
    }
    for (int b = threadIdx.x; b < K1; b += 1024) {
        int c = 0;
        #pragma unroll
        for (int k = 0; k < 4; ++k) {
            int f = 4 * b + k;
            if (f < KF) c += h[f];
        }
        cnt[b * C1_NBLK + blockIdx.x] = c;
    }
}

// One scan over KF fine counts -> fbase; cbase derived; offsets[N]=E.
__global__ void __launch_bounds__(1024) c1_scan_kernel(
        const int* __restrict__ ccount_f, int* __restrict__ fbase,
        int* __restrict__ cbase, int* __restrict__ offsets,
        int KF, int K1, int N, int E) {
    __shared__ int sc[1024];
    int t = threadIdx.x;
    int v = (t < KF) ? ccount_f[t] : 0;
    sc[t] = v;
    __syncthreads();
    for (int off = 1; off < 1024; off <<= 1) {
        int w = (t >= off) ? sc[t - off] : 0;
        __syncthreads();
        sc[t] += w;
        __syncthreads();
    }
    if (t < KF) fbase[t] = sc[t] - v;
    __syncthreads();
    if (t < K1) {
        int f = 4 * t;
        cbase[t] = (f < KF) ? (sc[f] - ccount_f[f]) : E;
    }
    if (t == 0) { fbase[KF] = E; cbase[K1] = E; offsets[N] = E; }
}

__global__ void __launch_bounds__(C1_NBLK) c1_cbase_kernel(
        const int* __restrict__ cnt, const int* __restrict__ cbase,
        int* __restrict__ base_tab) {
    __shared__ int sc[C1_NBLK];
    int b = blockIdx.x;
    int t = threadIdx.x;
    int v = cnt[b * C1_NBLK + t];
    sc[t] = v;
    __syncthreads();
    for (int off = 1; off < C1_NBLK; off <<= 1) {
        int w = (t >= off) ? sc[t - off] : 0;
        __syncthreads();
        sc[t] += w;
        __syncthreads();
    }
    base_tab[b * C1_NBLK + t] = cbase[b] + sc[t] - v;
}

// R17: subchunk LDS counting-sort + burst write. Writes for each output line
// arrive back-to-back from consecutive lanes -> L2 write-combining succeeds.
__global__ void __launch_bounds__(1024) c1_scatter_kernel(
        const int* __restrict__ dst, const int* __restrict__ src,
        const float4* __restrict__ sh, const int* __restrict__ base_tab,
        uint2* __restrict__ pay8A, int* __restrict__ packedA,
        int E, int K1, int EPB) {
    __shared__ uint2 spay[SCH];           // 32 KB
    __shared__ int   spk[SCH];            // 16 KB
    __shared__ unsigned char sbkt[SCH];   // 4 KB
    __shared__ int   hist[C1_MAXK];
    __shared__ int   lo[C1_MAXK];
    __shared__ int   scur[C1_MAXK];
    __shared__ int   gcur[C1_MAXK];
    __shared__ int   sc[C1_MAXK];
    int t = threadIdx.x;
    for (int b = t; b < K1; b += 1024)
        gcur[b] = base_tab[b * C1_NBLK + blockIdx.x];
    int base = blockIdx.x * EPB;
    int lim = min(EPB, E - base);

    for (int sb = 0; sb < lim; sb += SCH) {
        int sublen = min(SCH, lim - sb);
        for (int b = t; b < K1; b += 1024) hist[b] = 0;
        __syncthreads();
        int bk[4], pk[4];
        uint2 pv[4];
        bool vld[4];
        #pragma unroll
        for (int k = 0; k < 4; ++k) {
            int idx = t + k * 1024;
            vld[k] = (idx < sublen);
            if (vld[k]) {
                int e = base + sb + idx;
                int d = dst[e];
                bk[k] = d >> C1_LOG;
                float4 s4 = sh[e];
                pv[k] = make_uint2(f2bf(s4.x) | (f2bf(s4.y) << 16),
                                   f2bf(s4.z) | (f2bf(s4.w) << 16));
                pk[k] = ((d & (C1_NPB - 1)) << 21) | src[e];
                atomicAdd(&hist[bk[k]], 1);
            }
        }
        __syncthreads();
        if (t < C1_MAXK) sc[t] = (t < K1) ? hist[t] : 0;
        __syncthreads();
        for (int off = 1; off < C1_MAXK; off <<= 1) {
            int w = 0;
            if (t < C1_MAXK && t >= off) w = sc[t - off];
            __syncthreads();
            if (t < C1_MAXK) sc[t] += w;
            __syncthreads();
        }
        if (t < C1_MAXK) {
            int excl = sc[t] - ((t < K1) ? hist[t] : 0);
            lo[t] = excl;
            scur[t] = excl;
        }
        __syncthreads();
        #pragma unroll
        for (int k = 0; k < 4; ++k) {
            if (vld[k]) {
                int pos = atomicAdd(&scur[bk[k]], 1);
                spk[pos] = pk[k];
                spay[pos] = pv[k];
                sbkt[pos] = (unsigned char)bk[k];
            }
        }
        __syncthreads();
        for (int i = t; i < sublen; i += 1024) {
            int b = sbkt[i];
            int gd = gcur[b] + (i - lo[b]);
            packedA[gd] = spk[i];
            pay8A[gd] = spay[i];
        }
        __syncthreads();
        if (t < K1) gcur[t] += hist[t];
        __syncthreads();
    }
}

// R18: one block per fine bucket. SINGLE read of parent range: matching edges
// staged UNSORTED in LDS during the hist pass; after scan, place LDS->global
// sorted (scattered 12B writes inside the bucket's ~49KB L2-resident window).
// Fallback: if cnt > SCAP, old two-pass placement (correctness guard).
__global__ void __launch_bounds__(512) c2_sort_kernel(
        const int* __restrict__ cbase, const int* __restrict__ fbase,
        int* __restrict__ offsets, const uint2* __restrict__ pay8A,
        const int* __restrict__ packedA, uint2* __restrict__ pay8B,
        int* __restrict__ packedB, int N) {
    __shared__ uint2 spay[SCAP];          // 40 KB
    __shared__ int   spk[SCAP];           // 20 KB
    __shared__ int   hh[FINE_NPB];
    __shared__ int   scur[FINE_NPB];
    __shared__ int   stot;
    int fb = blockIdx.x;
    int t = threadIdx.x;
    int parent = fb >> 2, sub = fb & 3;
    int cbeg = cbase[parent], cend = cbase[parent + 1];
    int fbeg = fbase[fb];
    int cnt = fbase[fb + 1] - fbeg;
    if (t < FINE_NPB) hh[t] = 0;
    if (t == 0) stot = 0;
    __syncthreads();

    if (cnt <= SCAP) {
        // Fast path: one read of packedA; stage matching unsorted + hist.
        for (int i = cbeg + t; i < cend; i += 512) {
            int pk = packedA[i];
            int nc = (pk >> 21) & (C1_NPB - 1);
            if ((nc >> FINE_LOG) == sub) {
                atomicAdd(&hh[nc & (FINE_NPB - 1)], 1);
                int pos = atomicAdd(&stot, 1);
                spk[pos] = pk;
                spay[pos] = pay8A[i];
            }
        }
        __syncthreads();
        int v = (t < FINE_NPB) ? hh[t] : 0;
        if (t < FINE_NPB) hh[t] = v;
        __syncthreads();
        for (int off = 1; off < FINE_NPB; off <<= 1) {
            int w = (t < FINE_NPB && t >= off) ? hh[t - off] : 0;
            __syncthreads();
            if (t < FINE_NPB) hh[t] += w;
            __syncthreads();
        }
        if (t < FINE_NPB) {
            int excl = hh[t] - v;
            scur[t] = fbeg + excl;
            int node = (fb << FINE_LOG) + t;
            if (node < N) offsets[node] = fbeg + excl;
        }
        __syncthreads();
        // Place LDS -> global sorted (writes confined to 49KB window).
        for (int j = t; j < cnt; j += 512) {
            int pk = spk[j];
            int node = (pk >> 21) & (FINE_NPB - 1);
            int pos = atomicAdd(&scur[node], 1);
            packedB[pos] = pk;
            pay8B[pos] = spay[j];
        }
    } else {
        // Slow path (cnt > SCAP; ~never): R17's two-pass placement.
        for (int i = cbeg + t; i < cend; i += 512) {
            int nc = (packedA[i] >> 21) & (C1_NPB - 1);
            if ((nc >> FINE_LOG) == sub)
                atomicAdd(&hh[nc & (FINE_NPB - 1)], 1);
        }
        __syncthreads();
        int v = (t < FINE_NPB) ? hh[t] : 0;
        if (t < FINE_NPB) hh[t] = v;
        __syncthreads();
        for (int off = 1; off < FINE_NPB; off <<= 1) {
            int w = (t < FINE_NPB && t >= off) ? hh[t - off] : 0;
            __syncthreads();
            if (t < FINE_NPB) hh[t] += w;
            __syncthreads();
        }
        if (t < FINE_NPB) {
            int excl = hh[t] - v;
            scur[t] = fbeg + excl;
            int node = (fb << FINE_LOG) + t;
            if (node < N) offsets[node] = fbeg + excl;
        }
        __syncthreads();
        for (int i = cbeg + t; i < cend; i += 512) {
            int pk = packedA[i];
            int nc = (pk >> 21) & (C1_NPB - 1);
            if ((nc >> FINE_LOG) == sub) {
                int pos = atomicAdd(&scur[nc & (FINE_NPB - 1)], 1);
                packedB[pos] = pk;
                pay8B[pos] = pay8A[i];
            }
        }
    }
}

// R16 accum: 256-thr block = 4 waves; each wave handles 4 nodes (grp=lane>>4).
// Lane l=lane&15 covers u={2l,2l+1} via one ushort2 x-load. Per edge: 16-lane
// group broadcast-loads payload, 8 FMAs into a[8]. NO reduction, NO LDS.
__global__ void __launch_bounds__(256) accum_kernel(
        const unsigned short* __restrict__ xb, const uint2* __restrict__ pay8,
        const int* __restrict__ packed, const int* __restrict__ offsets,
        float* __restrict__ out, int smask, int N) {
    int wave = threadIdx.x >> 6;
    int lane = threadIdx.x & 63;
    int grp = lane >> 4;              // node within wave
    int l = lane & 15;                // covers u = 2l, 2l+1
    int n = blockIdx.x * 16 + wave * 4 + grp;
    if (n >= N) return;
    int beg = offsets[n], end = offsets[n + 1];
    int u2 = l << 1;
    float a0 = 0.f, a1 = 0.f, a2 = 0.f, a3 = 0.f;
    float a4 = 0.f, a5 = 0.f, a6 = 0.f, a7 = 0.f;
    int i = beg;
    for (; i + 3 < end; i += 4) {
        int pk0 = packed[i], pk1 = packed[i + 1];
        int pk2 = packed[i + 2], pk3 = packed[i + 3];
        uint2 q0 = pay8[i], q1 = pay8[i + 1];
        uint2 q2 = pay8[i + 2], q3 = pay8[i + 3];
        ushort2 xv0 = *reinterpret_cast<const ushort2*>(
            &xb[(size_t)(pk0 & smask) * U_DIM + u2]);
        ushort2 xv1 = *reinterpret_cast<const ushort2*>(
            &xb[(size_t)(pk1 & smask) * U_DIM + u2]);
        ushort2 xv2 = *reinterpret_cast<const ushort2*>(
            &xb[(size_t)(pk2 & smask) * U_DIM + u2]);
        ushort2 xv3 = *reinterpret_cast<const ushort2*>(
            &xb[(size_t)(pk3 & smask) * U_DIM + u2]);
        {
            float xa = bfl((unsigned)xv0.x), xc = bfl((unsigned)xv0.y);
            float s0 = bfl(q0.x), s1 = bfh(q0.x), s2 = bfl(q0.y), s3 = bfh(q0.y);
            a0 += xa * s0; a1 += xa * s1; a2 += xa * s2; a3 += xa * s3;
            a4 += xc * s0; a5 += xc * s1; a6 += xc * s2; a7 += xc * s3;
        }
        {
            float xa = bfl((unsigned)xv1.x), xc = bfl((unsigned)xv1.y);
            float s0 = bfl(q1.x), s1 = bfh(q1.x), s2 = bfl(q1.y), s3 = bfh(q1.y);
            a0 += xa * s0; a1 += xa * s1; a2 += xa * s2; a3 += xa * s3;
            a4 += xc * s0; a5 += xc * s1; a6 += xc * s2; a7 += xc * s3;
        }
        {
            float xa = bfl((unsigned)xv2.x), xc = bfl((unsigned)xv2.y);
            float s0 = bfl(q2.x), s1 = bfh(q2.x), s2 = bfl(q2.y), s3 = bfh(q2.y);
            a0 += xa * s0; a1 += xa * s1; a2 += xa * s2; a3 += xa * s3;
            a4 += xc * s0; a5 += xc * s1; a6 += xc * s2; a7 += xc * s3;
        }
        {
            float xa = bfl((unsigned)xv3.x), xc = bfl((unsigned)xv3.y);
            float s0 = bfl(q3.x), s1 = bfh(q3.x), s2 = bfl(q3.y), s3 = bfh(q3.y);
            a0 += xa * s0; a1 += xa * s1; a2 += xa * s2; a3 += xa * s3;
            a4 += xc * s0; a5 += xc * s1; a6 += xc * s2; a7 += xc * s3;
        }
    }
    for (; i < end; ++i) {
        int pk = packed[i];
        uint2 q = pay8[i];
        ushort2 xv = *reinterpret_cast<const ushort2*>(
            &xb[(size_t)(pk & smask) * U_DIM + u2]);
        float xa = bfl((unsigned)xv.x), xc = bfl((unsigned)xv.y);
        float s0 = bfl(q.x), s1 = bfh(q.x), s2 = bfl(q.y), s3 = bfh(q.y);
        a0 += xa * s0; a1 += xa * s1; a2 += xa * s2; a3 += xa * s3;
        a4 += xc * s0; a5 += xc * s1; a6 += xc * s2; a7 += xc * s3;
    }
    size_t obase = (size_t)n * US + (size_t)u2 * 4;
    *reinterpret_cast<float4*>(&out[obase])     = make_float4(a0, a1, a2, a3);
    *reinterpret_cast<float4*>(&out[obase + 4]) = make_float4(a4, a5, a6, a7);
}

// =================== TIER-2: proven R7 path ===================
#define LOG_NPBK 7
#define NPBK 128
#define MAXK 1024
#define NBLK 256
#define CAP 5120
#define SPILL_E 1000000

__global__ void __launch_bounds__(1024) coarse_hist_kernel(
        const int* __restrict__ dst, int* __restrict__ ccount,
        int* __restrict__ cnt, int E, int K, int EPB) {
    __shared__ int h[MAXK];
    for (int b = threadIdx.x; b < K; b += 1024) h[b] = 0;
    __syncthreads();
    int base = blockIdx.x * EPB;
    int lim = min(EPB, E - base);
    for (int i = threadIdx.x; i < lim; i += 1024)
        atomicAdd(&h[dst[base + i] >> LOG_NPBK], 1);
    __syncthreads();
    for (int b = threadIdx.x; b < K; b += 1024) {
        int c = h[b];
        cnt[b * NBLK + blockIdx.x] = c;
        if (c) atomicAdd(&ccount[b], c);
    }
}

__global__ void __launch_bounds__(1024) coarse_scan_kernel(
        const int* __restrict__ ccount, int* __restrict__ cbase,
        int* __restrict__ offsets, int* __restrict__ spill_cursor,
        int K, int N, int E) {
    __shared__ int sc[1024];
    int t = threadIdx.x;
    int v = (t < K) ? ccount[t] : 0;
    sc[t] = v;
    __syncthreads();
    for (int off = 1; off < 1024; off <<= 1) {
        int w = (t >= off) ? sc[t - off] : 0;
        __syncthreads();
        sc[t] += w;
        __syncthreads();
    }
    if (t < K) cbase[t] = sc[t] - v;
    if (t == 0) { cbase[K] = E; offsets[N] = E; *spill_cursor = 0; }
}

__global__ void __launch_bounds__(NBLK) chunk_base_kernel(
        const int* __restrict__ cnt, const int* __restrict__ cbase,
        int* __restrict__ base_tab) {
    __shared__ int sc[NBLK];
    int b = blockIdx.x;
    int t = threadIdx.x;
    int v = cnt[b * NBLK + t];
    sc[t] = v;
    __syncthreads();
    for (int off = 1; off < NBLK; off <<= 1) {
        int w = (t >= off) ? sc[t - off] : 0;
        __syncthreads();
        sc[t] += w;
        __syncthreads();
    }
    base_tab[b * NBLK + t] = cbase[b] + sc[t] - v;
}

__global__ void __launch_bounds__(1024) coarse_scatter_kernel(
        const int* __restrict__ dst, const int* __restrict__ src,
        const float4* __restrict__ sh, const int* __restrict__ base_tab,
        uint2* __restrict__ pay8, int* __restrict__ packed,
        int E, int K, int EPB) {
    __shared__ int cur[MAXK];
    for (int b = threadIdx.x; b < K; b += 1024)
        cur[b] = base_tab[b * NBLK + blockIdx.x];
    __syncthreads();
    int base = blockIdx.x * EPB;
    int lim = min(EPB, E - base);
    for (int i = threadIdx.x; i < lim; i += 1024) {
        int e = base + i;
        int d = dst[e];
        int b = d >> LOG_NPBK;
        int pos = atomicAdd(&cur[b], 1);
        float4 s4 = sh[e];
        pay8[pos] = make_uint2(f2bf(s4.x) | (f2bf(s4.y) << 16),
                               f2bf(s4.z) | (f2bf(s4.w) << 16));
        packed[pos] = ((d & (NPBK - 1)) << 24) | src[e];
    }
}

__global__ void __launch_bounds__(512) fine_sort_kernel(
        const int* __restrict__ cbase, int* __restrict__ offsets,
        uint2* __restrict__ pay8, int* __restrict__ packed,
        uint2* __restrict__ spill_pay, int* __restrict__ spill_pk,
        int* __restrict__ spill_cursor, int N) {
    __shared__ uint2 spay[CAP];
    __shared__ int   spk[CAP];
    __shared__ int   cnt_[NPBK];
    __shared__ int   sc[NPBK];
    __shared__ int   sbase_s;
    int b = blockIdx.x;
    int t = threadIdx.x;
    int cbeg = cbase[b], cend = cbase[b + 1];
    int cnt = cend - cbeg;
    if (t == 0) sbase_s = (cnt > CAP) ? atomicAdd(spill_cursor, cnt - CAP) : 0;
    if (t < NPBK) cnt_[t] = 0;
    __syncthreads();
    for (int i = t; i < cnt; i += 512) {
        int pk = packed[cbeg + i];
        uint2 p8 = pay8[cbeg + i];
        atomicAdd(&cnt_[(pk >> 24) & (NPBK - 1)], 1);
        if (i < CAP) { spk[i] = pk; spay[i] = p8; }
        else {
            int sp = sbase_s + (i - CAP);
            if (sp < SPILL_E) { spill_pk[sp] = pk; spill_pay[sp] = p8; }
        }
    }
    __syncthreads();
    int v = (t < NPBK) ? cnt_[t] : 0;
    if (t < NPBK) sc[t] = v;
    __syncthreads();
    for (int off = 1; off < NPBK; off <<= 1) {
        int w = (t < NPBK && t >= off) ? sc[t - off] : 0;
        __syncthreads();
        if (t < NPBK) sc[t] += w;
        __syncthreads();
    }
    if (t < NPBK) {
        int ex = sc[t] - v;
        int node = (b << LOG_NPBK) + t;
        if (node <= N) offsets[node] = cbeg + ex;
        cnt_[t] = ex;
    }
    __syncthreads();
    for (int i = t; i < cnt; i += 512) {
        int pk; uint2 p8;
        bool ok = true;
        if (i < CAP) { pk = spk[i]; p8 = spay[i]; }
        else {
            int sp = sbase_s + (i - CAP);
            ok = (sp < SPILL_E);
            if (ok) { pk = spill_pk[sp]; p8 = spill_pay[sp]; }
        }
        if (ok) {
            int pos = cbeg + atomicAdd(&cnt_[(pk >> 24) & (NPBK - 1)], 1);
            packed[pos] = pk;
            pay8[pos] = p8;
        }
    }
}

// --- Fallback tiers 3/4 ---
constexpr int SCAN_BLOCK = 256;
constexpr int SCAN_ITEMS = 8;
constexpr int SCAN_CHUNK = SCAN_BLOCK * SCAN_ITEMS;

__global__ void __launch_bounds__(256) hist_kernel(
        const int* __restrict__ dst, int* __restrict__ counts, int E) {
    int e = blockIdx.x * blockDim.x + threadIdx.x;
    if (e < E) atomicAdd(&counts[dst[e]], 1);
}
__global__ void __launch_bounds__(SCAN_BLOCK) block_sum_kernel(
        const int* __restrict__ counts, int* __restrict__ bsums, int N) {
    __shared__ int sdata[SCAN_BLOCK];
    int base = blockIdx.x * SCAN_CHUNK;
    int sum = 0;
    for (int j = 0; j < SCAN_ITEMS; ++j) {
        int idx = base + j * SCAN_BLOCK + threadIdx.x;
        if (idx < N) sum += counts[idx];
    }
    sdata[threadIdx.x] = sum;
    __syncthreads();
    for (int off = SCAN_BLOCK / 2; off > 0; off >>= 1) {
        if (threadIdx.x < off) sdata[threadIdx.x] += sdata[threadIdx.x + off];
        __syncthreads();
    }
    if (threadIdx.x == 0) bsums[blockIdx.x] = sdata[0];
}
__global__ void scan_bsums_kernel(int* __restrict__ bsums, int nb) {
    if (threadIdx.x == 0 && blockIdx.x == 0) {
        int acc = 0;
        for (int i = 0; i < nb; ++i) { int v = bsums[i]; bsums[i] = acc; acc += v; }
    }
}
__global__ void __launch_bounds__(SCAN_BLOCK) scan_final_kernel(
        const int* __restrict__ counts, const int* __restrict__ bsums,
        int* __restrict__ offsets, int* __restrict__ cursors, int N, int E) {
    __shared__ int sdata[SCAN_BLOCK];
    int base = blockIdx.x * SCAN_CHUNK + threadIdx.x * SCAN_ITEMS;
    int local[SCAN_ITEMS];
    int tsum = 0;
    for (int j = 0; j < SCAN_ITEMS; ++j) {
        int idx = base + j;
        int v = (idx < N) ? counts[idx] : 0;
        local[j] = tsum;
        tsum += v;
    }
    sdata[threadIdx.x] = tsum;
    __syncthreads();
    for (int off = 1; off < SCAN_BLOCK; off <<= 1) {
        int v = (threadIdx.x >= off) ? sdata[threadIdx.x - off] : 0;
        __syncthreads();
        sdata[threadIdx.x] += v;
        __syncthreads();
    }
    int excl = sdata[threadIdx.x] - tsum + bsums[blockIdx.x];
    for (int j = 0; j < SCAN_ITEMS; ++j) {
        int idx = base + j;
        if (idx < N) { int o = excl + local[j]; offsets[idx] = o; cursors[idx] = o; }
    }
    if (blockIdx.x == 0 && threadIdx.x == 0) offsets[N] = E;
}
__global__ void __launch_bounds__(256) scatter_ids_kernel(
        const int* __restrict__ dst, int* __restrict__ cursors,
        int* __restrict__ eids, int E) {
    int e = blockIdx.x * blockDim.x + threadIdx.x;
    if (e < E) { int pos = atomicAdd(&cursors[dst[e]], 1); eids[pos] = e; }
}
__global__ void __launch_bounds__(US) accum_ids_kernel(
        const float* __restrict__ x, const float* __restrict__ sh,
        const int* __restrict__ src, const int* __restrict__ offsets,
        const int* __restrict__ eids, float* __restrict__ out) {
    int n = blockIdx.x;
    int t = threadIdx.x;
    int u = t >> 2, s = t & 3;
    int beg = offsets[n], end = offsets[n + 1];
    float acc = 0.f;
    for (int i = beg; i < end; ++i) {
        int e = eids[i];
        acc += x[src[e] * U_DIM + u] * sh[e * 4 + s];
    }
    out[(size_t)n * US + t] = acc;
}
__global__ void __launch_bounds__(US) atomic_kernel(
        const float* __restrict__ x, const float* __restrict__ sh,
        const int* __restrict__ src, const int* __restrict__ dst,
        float* __restrict__ out, int E) {
    int e = blockIdx.x;
    int t = threadIdx.x;
    float v = x[src[e] * U_DIM + (t >> 2)] * sh[e * 4 + (t & 3)];
    atomicAdd(&out[(size_t)dst[e] * US + t], v);
}

extern "C" void kernel_launch(void* const* d_in, const int* in_sizes, int n_in,
                              void* d_out, int out_size, void* d_ws, size_t ws_size,
                              hipStream_t stream) {
    const float* x  = (const float*)d_in[0];
    const float* sh = (const float*)d_in[1];
    const int* src  = (const int*)d_in[2];
    const int* dst  = (const int*)d_in[3];
    float* out = (float*)d_out;

    const int E = in_sizes[2];
    const int N = in_sizes[0] / U_DIM;
    const int xn4 = in_sizes[0] / 4;
    const int egrid = (E + 255) / 256;
    const int nb = (N + SCAN_CHUNK - 1) / SCAN_CHUNK;

    const int K1 = (N + C1_NPB - 1) >> C1_LOG;
    const int KF = (N + FINE_NPB - 1) >> FINE_LOG;
    const int EPB1 = (E + C1_NBLK - 1) / C1_NBLK;
    size_t need_main = (size_t)E * 24 + (size_t)in_sizes[0] * 2 +
                       (size_t)(N + 1 + 2 * KF + 2 + K1 + 1 +
                                2 * K1 * C1_NBLK) * 4;

    const int K = (N + NPBK - 1) >> LOG_NPBK;
    const int EPB = (E + NBLK - 1) / NBLK;
    size_t need_r7 = (size_t)E * 12 + (size_t)SPILL_E * 12 + (size_t)(N + 1) * 4 +
                     (size_t)(2 * K + 2) * 4 + (size_t)(2 * K * NBLK) * 4 +
                     (size_t)in_sizes[0] * 2;
    size_t need_ids = (size_t)E * 4 + (size_t)(3 * N + 1 + nb) * 4;

    if (K1 <= C1_MAXK && KF <= KF_MAX && N <= (1 << 21) &&
        (in_sizes[0] % 4 == 0) && ws_size >= need_main) {
        uint2* pay8A   = (uint2*)d_ws;
        uint2* pay8B   = pay8A + E;
        int* packedA   = (int*)(pay8B + E);
        int* packedB   = packedA + E;
        unsigned short* xb = (unsigned short*)(packedB + E);
        int* offsets   = (int*)(xb + in_sizes[0]);
        int* ccount_f  = offsets + N + 1;
        int* fbase     = ccount_f + KF;
        int* cbase     = fbase + KF + 1;
        int* cnt       = cbase + K1 + 1;
        int* base_tab  = cnt + K1 * C1_NBLK;

        hipMemsetAsync(ccount_f, 0, sizeof(int) * (size_t)KF, stream);
        xcvt_kernel<<<(xn4 + 255) / 256, 256, 0, stream>>>(
            (const float4*)x, (ushort4*)xb, xn4);
        c1_hist_kernel<<<C1_NBLK, 1024, 0, stream>>>(dst, ccount_f, cnt,
                                                     E, KF, K1, EPB1);
        c1_scan_kernel<<<1, 1024, 0, stream>>>(ccount_f, fbase, cbase, offsets,
                                               KF, K1, N, E);
        c1_cbase_kernel<<<K1, C1_NBLK, 0, stream>>>(cnt, cbase, base_tab);
        c1_scatter_kernel<<<C1_NBLK, 1024, 0, stream>>>(dst, src, (const float4*)sh,
                                                        base_tab, pay8A, packedA,
                                                        E, K1, EPB1);
        c2_sort_kernel<<<KF, 512, 0, stream>>>(cbase, fbase, offsets,
                                               pay8A, packedA, pay8B, packedB, N);
        accum_kernel<<<(N + 15) / 16, 256, 0, stream>>>(xb, pay8B, packedB,
                                                        offsets, out, 0x1FFFFF, N);
    } else if (K <= MAXK && (in_sizes[0] % 4 == 0) && ws_size >= need_r7) {
        uint2* pay8      = (uint2*)d_ws;
        uint2* spill_pay = pay8 + E;
        int* packed      = (int*)(spill_pay + SPILL_E);
        int* spill_pk    = packed + E;
        int* offsets     = spill_pk + SPILL_E;
        int* ccount      = offsets + N + 1;
        int* cbase       = ccount + K;
        int* cnt         = cbase + K + 1;
        int* base_tab    = cnt + K * NBLK;
        int* spill_cur   = base_tab + K * NBLK;
        unsigned short* xb = (unsigned short*)(spill_cur + 1);

        hipMemsetAsync(ccount, 0, sizeof(int) * (size_t)K, stream);
        xcvt_kernel<<<(xn4 + 255) / 256, 256, 0, stream>>>(
            (const float4*)x, (ushort4*)xb, xn4);
        coarse_hist_kernel<<<NBLK, 1024, 0, stream>>>(dst, ccount, cnt, E, K, EPB);
        coarse_scan_kernel<<<1, 1024, 0, stream>>>(ccount, cbase, offsets,
                                                   spill_cur, K, N, E);
        chunk_base_kernel<<<K, NBLK, 0, stream>>>(cnt, cbase, base_tab);
        coarse_scatter_kernel<<<NBLK, 1024, 0, stream>>>(dst, src, (const float4*)sh,
                                                         base_tab, pay8, packed,
                                                         E, K, EPB);
        fine_sort_kernel<<<K, 512, 0, stream>>>(cbase, offsets, pay8, packed,
                                                spill_pay, spill_pk, spill_cur, N);
        accum_kernel<<<(N + 15) / 16, 256, 0, stream>>>(xb, pay8, packed,
                                                        offsets, out, 0xFFFFFF, N);
    } else if (ws_size >= need_ids) {
        int* eids    = (int*)d_ws;
        int* counts  = eids + E;
        int* offsets = counts + N;
        int* cursors = offsets + N + 1;
        int* bsums   = cursors + N;

        hipMemsetAsync(counts, 0, sizeof(int) * (size_t)N, stream);
        hist_kernel<<<egrid, 256, 0, stream>>>(dst, counts, E);
        block_sum_kernel<<<nb, SCAN_BLOCK, 0, stream>>>(counts, bsums, N);
        scan_bsums_kernel<<<1, 64, 0, stream>>>(bsums, nb);
        scan_final_kernel<<<nb, SCAN_BLOCK, 0, stream>>>(counts, bsums, offsets, cursors, N, E);
        scatter_ids_kernel<<<egrid, 256, 0, stream>>>(dst, cursors, eids, E);
        accum_ids_kernel<<<N, US, 0, stream>>>(x, sh, src, offsets, eids, out);
    } else {
        hipMemsetAsync(out, 0, sizeof(float) * (size_t)out_size, stream);
        atomic_kernel<<<E, US, 0, stream>>>(x, sh, src, dst, out, E);
    }
}

// Round 19
// 187.600 us; speedup vs baseline: 1.0504x; 1.0504x over previous
//
#include <hip/hip_runtime.h>

// out[n, u*4+s] = sum_{e: dst[e]==n} x[src[e], u] * sh[e, s]
// N=100000, U=32, S=4, E=3200000.
//
// Ledger of lessons:
//  R2: bulk LDS float atomics / single-counter atomics = serial floor.
//  R4/R5/R7: scattered writes, many streams/block = HBM write amp.
//  R8: few deep-serial blocks lose to many shallow blocks.
//  R9/R13: xb/sh are L3-resident; FETCH is L2-fill traffic.
//  R10: NT loads on shared streams re-fetch lines.
//  R11/R15/R16: accum: contiguous ranges, 4 nodes/wave, 16 lanes/edge.
//  R12: lane-widening + cross-lane reduction = loss.
//  R13: XCD-swizzle on undefined block->XCD mapping: reverted.
//  R17: c1 subchunk LDS-sort + burst write kills write amp.
//  R18: c2 single-read (FETCH 94.6->74.6MB) but dur flat -> LATENCY-bound
//       (29% occ: 61.5KB LDS -> 2 blk/CU x 512 thr = 16 waves/CU).
// R19: c2_sort 512->1024 threads (2 blk/CU x 1024 = 32 waves/CU = 100%)
//      + wave-aggregated ballot reservation for the stage counter.

#define U_DIM 32
#define US 128

__device__ inline unsigned f2bf(float f) {          // RNE float->bf16 bits
    unsigned u = __float_as_uint(f);
    return (u + 0x7FFF + ((u >> 16) & 1)) >> 16;
}
__device__ inline float bfl(unsigned w) { return __uint_as_float(w << 16); }
__device__ inline float bfh(unsigned w) { return __uint_as_float(w & 0xFFFF0000u); }

__global__ void __launch_bounds__(256) xcvt_kernel(
        const float4* __restrict__ x4, ushort4* __restrict__ xb4, int n4) {
    int i = blockIdx.x * 256 + threadIdx.x;
    if (i < n4) {
        float4 v = x4[i];
        ushort4 r;
        r.x = (unsigned short)f2bf(v.x);
        r.y = (unsigned short)f2bf(v.y);
        r.z = (unsigned short)f2bf(v.z);
        r.w = (unsigned short)f2bf(v.w);
        xb4[i] = r;
    }
}

// =================== PRIMARY PATH ===================
#define C1_LOG 9
#define C1_NPB 512
#define C1_MAXK 256
#define C1_NBLK 256
#define FINE_LOG 7
#define FINE_NPB 128
#define KF_MAX 1024
#define SCAP 5120             // LDS-staged edges per fine bucket (mean 4082)
#define SCH 4096              // c1_scatter subchunk (LDS-sorted burst unit)

// Fine-granularity (128-node) histogram; also per-chunk coarse counts.
__global__ void __launch_bounds__(1024) c1_hist_kernel(
        const int* __restrict__ dst, int* __restrict__ ccount_f,
        int* __restrict__ cnt, int E, int KF, int K1, int EPB) {
    __shared__ int h[KF_MAX];
    for (int b = threadIdx.x; b < KF; b += 1024) h[b] = 0;
    __syncthreads();
    int base = blockIdx.x * EPB;
    int lim = min(EPB, E - base);
    for (int i = threadIdx.x; i < lim; i += 1024)
        atomicAdd(&h[dst[base + i] >> FINE_LOG], 1);
    __syncthreads();
    for (int b = threadIdx.x; b < KF; b += 1024) {
        int c = h[b];
        if (c) atomicAdd(&ccount_f[b], c);
    }
    for (int b = threadIdx.x; b < K1; b += 1024) {
        int c = 0;
        #pragma unroll
        for (int k = 0; k < 4; ++k) {
            int f = 4 * b + k;
            if (f < KF) c += h[f];
        }
        cnt[b * C1_NBLK + blockIdx.x] = c;
    }
}

// One scan over KF fine counts -> fbase; cbase derived; offsets[N]=E.
__global__ void __launch_bounds__(1024) c1_scan_kernel(
        const int* __restrict__ ccount_f, int* __restrict__ fbase,
        int* __restrict__ cbase, int* __restrict__ offsets,
        int KF, int K1, int N, int E) {
    __shared__ int sc[1024];
    int t = threadIdx.x;
    int v = (t < KF) ? ccount_f[t] : 0;
    sc[t] = v;
    __syncthreads();
    for (int off = 1; off < 1024; off <<= 1) {
        int w = (t >= off) ? sc[t - off] : 0;
        __syncthreads();
        sc[t] += w;
        __syncthreads();
    }
    if (t < KF) fbase[t] = sc[t] - v;
    __syncthreads();
    if (t < K1) {
        int f = 4 * t;
        cbase[t] = (f < KF) ? (sc[f] - ccount_f[f]) : E;
    }
    if (t == 0) { fbase[KF] = E; cbase[K1] = E; offsets[N] = E; }
}

__global__ void __launch_bounds__(C1_NBLK) c1_cbase_kernel(
        const int* __restrict__ cnt, const int* __restrict__ cbase,
        int* __restrict__ base_tab) {
    __shared__ int sc[C1_NBLK];
    int b = blockIdx.x;
    int t = threadIdx.x;
    int v = cnt[b * C1_NBLK + t];
    sc[t] = v;
    __syncthreads();
    for (int off = 1; off < C1_NBLK; off <<= 1) {
        int w = (t >= off) ? sc[t - off] : 0;
        __syncthreads();
        sc[t] += w;
        __syncthreads();
    }
    base_tab[b * C1_NBLK + t] = cbase[b] + sc[t] - v;
}

// R17: subchunk LDS counting-sort + burst write. Writes for each output line
// arrive back-to-back from consecutive lanes -> L2 write-combining succeeds.
__global__ void __launch_bounds__(1024) c1_scatter_kernel(
        const int* __restrict__ dst, const int* __restrict__ src,
        const float4* __restrict__ sh, const int* __restrict__ base_tab,
        uint2* __restrict__ pay8A, int* __restrict__ packedA,
        int E, int K1, int EPB) {
    __shared__ uint2 spay[SCH];           // 32 KB
    __shared__ int   spk[SCH];            // 16 KB
    __shared__ unsigned char sbkt[SCH];   // 4 KB
    __shared__ int   hist[C1_MAXK];
    __shared__ int   lo[C1_MAXK];
    __shared__ int   scur[C1_MAXK];
    __shared__ int   gcur[C1_MAXK];
    __shared__ int   sc[C1_MAXK];
    int t = threadIdx.x;
    for (int b = t; b < K1; b += 1024)
        gcur[b] = base_tab[b * C1_NBLK + blockIdx.x];
    int base = blockIdx.x * EPB;
    int lim = min(EPB, E - base);

    for (int sb = 0; sb < lim; sb += SCH) {
        int sublen = min(SCH, lim - sb);
        for (int b = t; b < K1; b += 1024) hist[b] = 0;
        __syncthreads();
        int bk[4], pk[4];
        uint2 pv[4];
        bool vld[4];
        #pragma unroll
        for (int k = 0; k < 4; ++k) {
            int idx = t + k * 1024;
            vld[k] = (idx < sublen);
            if (vld[k]) {
                int e = base + sb + idx;
                int d = dst[e];
                bk[k] = d >> C1_LOG;
                float4 s4 = sh[e];
                pv[k] = make_uint2(f2bf(s4.x) | (f2bf(s4.y) << 16),
                                   f2bf(s4.z) | (f2bf(s4.w) << 16));
                pk[k] = ((d & (C1_NPB - 1)) << 21) | src[e];
                atomicAdd(&hist[bk[k]], 1);
            }
        }
        __syncthreads();
        if (t < C1_MAXK) sc[t] = (t < K1) ? hist[t] : 0;
        __syncthreads();
        for (int off = 1; off < C1_MAXK; off <<= 1) {
            int w = 0;
            if (t < C1_MAXK && t >= off) w = sc[t - off];
            __syncthreads();
            if (t < C1_MAXK) sc[t] += w;
            __syncthreads();
        }
        if (t < C1_MAXK) {
            int excl = sc[t] - ((t < K1) ? hist[t] : 0);
            lo[t] = excl;
            scur[t] = excl;
        }
        __syncthreads();
        #pragma unroll
        for (int k = 0; k < 4; ++k) {
            if (vld[k]) {
                int pos = atomicAdd(&scur[bk[k]], 1);
                spk[pos] = pk[k];
                spay[pos] = pv[k];
                sbkt[pos] = (unsigned char)bk[k];
            }
        }
        __syncthreads();
        for (int i = t; i < sublen; i += 1024) {
            int b = sbkt[i];
            int gd = gcur[b] + (i - lo[b]);
            packedA[gd] = spk[i];
            pay8A[gd] = spay[i];
        }
        __syncthreads();
        if (t < K1) gcur[t] += hist[t];
        __syncthreads();
    }
}

// R19: one block per fine bucket, 1024 threads (2 blk/CU x 1024 = 32 waves/CU).
// Single read of parent range; matching edges staged UNSORTED in LDS (wave-
// aggregated ballot reservation), then placed LDS->global sorted.
__global__ void __launch_bounds__(1024) c2_sort_kernel(
        const int* __restrict__ cbase, const int* __restrict__ fbase,
        int* __restrict__ offsets, const uint2* __restrict__ pay8A,
        const int* __restrict__ packedA, uint2* __restrict__ pay8B,
        int* __restrict__ packedB, int N) {
    __shared__ uint2 spay[SCAP];          // 40 KB
    __shared__ int   spk[SCAP];           // 20 KB
    __shared__ int   hh[FINE_NPB];
    __shared__ int   scur[FINE_NPB];
    __shared__ int   stot;
    int fb = blockIdx.x;
    int t = threadIdx.x;
    int lane = t & 63;
    int parent = fb >> 2, sub = fb & 3;
    int cbeg = cbase[parent], cend = cbase[parent + 1];
    int fbeg = fbase[fb];
    int cnt = fbase[fb + 1] - fbeg;
    if (t < FINE_NPB) hh[t] = 0;
    if (t == 0) stot = 0;
    __syncthreads();

    if (cnt <= SCAP) {
        // Single read of packedA; ballot-aggregated staging + hist.
        for (int i = cbeg + t; i < cend; i += 1024) {
            int pk = packedA[i];
            int nc = (pk >> 21) & (C1_NPB - 1);
            bool m = ((nc >> FINE_LOG) == sub);
            unsigned long long mask = __ballot(m);
            if (m) {
                atomicAdd(&hh[nc & (FINE_NPB - 1)], 1);
                int leader = __ffsll((long long)mask) - 1;
                int base_ = 0;
                if (lane == leader) base_ = atomicAdd(&stot, __popcll(mask));
                base_ = __shfl(base_, leader);
                int pos = base_ + __popcll(mask & ((1ull << lane) - 1ull));
                spk[pos] = pk;
                spay[pos] = pay8A[i];
            }
        }
        __syncthreads();
        int v = (t < FINE_NPB) ? hh[t] : 0;
        if (t < FINE_NPB) hh[t] = v;
        __syncthreads();
        for (int off = 1; off < FINE_NPB; off <<= 1) {
            int w = (t < FINE_NPB && t >= off) ? hh[t - off] : 0;
            __syncthreads();
            if (t < FINE_NPB) hh[t] += w;
            __syncthreads();
        }
        if (t < FINE_NPB) {
            int excl = hh[t] - v;
            scur[t] = fbeg + excl;
            int node = (fb << FINE_LOG) + t;
            if (node < N) offsets[node] = fbeg + excl;
        }
        __syncthreads();
        // Place LDS -> global sorted (writes confined to ~49KB window).
        for (int j = t; j < cnt; j += 1024) {
            int pk = spk[j];
            int node = (pk >> 21) & (FINE_NPB - 1);
            int pos = atomicAdd(&scur[node], 1);
            packedB[pos] = pk;
            pay8B[pos] = spay[j];
        }
    } else {
        // Slow path (cnt > SCAP; ~never): two-pass placement.
        for (int i = cbeg + t; i < cend; i += 1024) {
            int nc = (packedA[i] >> 21) & (C1_NPB - 1);
            if ((nc >> FINE_LOG) == sub)
                atomicAdd(&hh[nc & (FINE_NPB - 1)], 1);
        }
        __syncthreads();
        int v = (t < FINE_NPB) ? hh[t] : 0;
        if (t < FINE_NPB) hh[t] = v;
        __syncthreads();
        for (int off = 1; off < FINE_NPB; off <<= 1) {
            int w = (t < FINE_NPB && t >= off) ? hh[t - off] : 0;
            __syncthreads();
            if (t < FINE_NPB) hh[t] += w;
            __syncthreads();
        }
        if (t < FINE_NPB) {
            int excl = hh[t] - v;
            scur[t] = fbeg + excl;
            int node = (fb << FINE_LOG) + t;
            if (node < N) offsets[node] = fbeg + excl;
        }
        __syncthreads();
        for (int i = cbeg + t; i < cend; i += 1024) {
            int pk = packedA[i];
            int nc = (pk >> 21) & (C1_NPB - 1);
            if ((nc >> FINE_LOG) == sub) {
                int pos = atomicAdd(&scur[nc & (FINE_NPB - 1)], 1);
                packedB[pos] = pk;
                pay8B[pos] = pay8A[i];
            }
        }
    }
}

// R16 accum: 256-thr block = 4 waves; each wave handles 4 nodes (grp=lane>>4).
// Lane l=lane&15 covers u={2l,2l+1} via one ushort2 x-load. NO reduction.
__global__ void __launch_bounds__(256) accum_kernel(
        const unsigned short* __restrict__ xb, const uint2* __restrict__ pay8,
        const int* __restrict__ packed, const int* __restrict__ offsets,
        float* __restrict__ out, int smask, int N) {
    int wave = threadIdx.x >> 6;
    int lane = threadIdx.x & 63;
    int grp = lane >> 4;              // node within wave
    int l = lane & 15;                // covers u = 2l, 2l+1
    int n = blockIdx.x * 16 + wave * 4 + grp;
    if (n >= N) return;
    int beg = offsets[n], end = offsets[n + 1];
    int u2 = l << 1;
    float a0 = 0.f, a1 = 0.f, a2 = 0.f, a3 = 0.f;
    float a4 = 0.f, a5 = 0.f, a6 = 0.f, a7 = 0.f;
    int i = beg;
    for (; i + 3 < end; i += 4) {
        int pk0 = packed[i], pk1 = packed[i + 1];
        int pk2 = packed[i + 2], pk3 = packed[i + 3];
        uint2 q0 = pay8[i], q1 = pay8[i + 1];
        uint2 q2 = pay8[i + 2], q3 = pay8[i + 3];
        ushort2 xv0 = *reinterpret_cast<const ushort2*>(
            &xb[(size_t)(pk0 & smask) * U_DIM + u2]);
        ushort2 xv1 = *reinterpret_cast<const ushort2*>(
            &xb[(size_t)(pk1 & smask) * U_DIM + u2]);
        ushort2 xv2 = *reinterpret_cast<const ushort2*>(
            &xb[(size_t)(pk2 & smask) * U_DIM + u2]);
        ushort2 xv3 = *reinterpret_cast<const ushort2*>(
            &xb[(size_t)(pk3 & smask) * U_DIM + u2]);
        {
            float xa = bfl((unsigned)xv0.x), xc = bfl((unsigned)xv0.y);
            float s0 = bfl(q0.x), s1 = bfh(q0.x), s2 = bfl(q0.y), s3 = bfh(q0.y);
            a0 += xa * s0; a1 += xa * s1; a2 += xa * s2; a3 += xa * s3;
            a4 += xc * s0; a5 += xc * s1; a6 += xc * s2; a7 += xc * s3;
        }
        {
            float xa = bfl((unsigned)xv1.x), xc = bfl((unsigned)xv1.y);
            float s0 = bfl(q1.x), s1 = bfh(q1.x), s2 = bfl(q1.y), s3 = bfh(q1.y);
            a0 += xa * s0; a1 += xa * s1; a2 += xa * s2; a3 += xa * s3;
            a4 += xc * s0; a5 += xc * s1; a6 += xc * s2; a7 += xc * s3;
        }
        {
            float xa = bfl((unsigned)xv2.x), xc = bfl((unsigned)xv2.y);
            float s0 = bfl(q2.x), s1 = bfh(q2.x), s2 = bfl(q2.y), s3 = bfh(q2.y);
            a0 += xa * s0; a1 += xa * s1; a2 += xa * s2; a3 += xa * s3;
            a4 += xc * s0; a5 += xc * s1; a6 += xc * s2; a7 += xc * s3;
        }
        {
            float xa = bfl((unsigned)xv3.x), xc = bfl((unsigned)xv3.y);
            float s0 = bfl(q3.x), s1 = bfh(q3.x), s2 = bfl(q3.y), s3 = bfh(q3.y);
            a0 += xa * s0; a1 += xa * s1; a2 += xa * s2; a3 += xa * s3;
            a4 += xc * s0; a5 += xc * s1; a6 += xc * s2; a7 += xc * s3;
        }
    }
    for (; i < end; ++i) {
        int pk = packed[i];
        uint2 q = pay8[i];
        ushort2 xv = *reinterpret_cast<const ushort2*>(
            &xb[(size_t)(pk & smask) * U_DIM + u2]);
        float xa = bfl((unsigned)xv.x), xc = bfl((unsigned)xv.y);
        float s0 = bfl(q.x), s1 = bfh(q.x), s2 = bfl(q.y), s3 = bfh(q.y);
        a0 += xa * s0; a1 += xa * s1; a2 += xa * s2; a3 += xa * s3;
        a4 += xc * s0; a5 += xc * s1; a6 += xc * s2; a7 += xc * s3;
    }
    size_t obase = (size_t)n * US + (size_t)u2 * 4;
    *reinterpret_cast<float4*>(&out[obase])     = make_float4(a0, a1, a2, a3);
    *reinterpret_cast<float4*>(&out[obase + 4]) = make_float4(a4, a5, a6, a7);
}

// =================== TIER-2: proven R7 path ===================
#define LOG_NPBK 7
#define NPBK 128
#define MAXK 1024
#define NBLK 256
#define CAP 5120
#define SPILL_E 1000000

__global__ void __launch_bounds__(1024) coarse_hist_kernel(
        const int* __restrict__ dst, int* __restrict__ ccount,
        int* __restrict__ cnt, int E, int K, int EPB) {
    __shared__ int h[MAXK];
    for (int b = threadIdx.x; b < K; b += 1024) h[b] = 0;
    __syncthreads();
    int base = blockIdx.x * EPB;
    int lim = min(EPB, E - base);
    for (int i = threadIdx.x; i < lim; i += 1024)
        atomicAdd(&h[dst[base + i] >> LOG_NPBK], 1);
    __syncthreads();
    for (int b = threadIdx.x; b < K; b += 1024) {
        int c = h[b];
        cnt[b * NBLK + blockIdx.x] = c;
        if (c) atomicAdd(&ccount[b], c);
    }
}

__global__ void __launch_bounds__(1024) coarse_scan_kernel(
        const int* __restrict__ ccount, int* __restrict__ cbase,
        int* __restrict__ offsets, int* __restrict__ spill_cursor,
        int K, int N, int E) {
    __shared__ int sc[1024];
    int t = threadIdx.x;
    int v = (t < K) ? ccount[t] : 0;
    sc[t] = v;
    __syncthreads();
    for (int off = 1; off < 1024; off <<= 1) {
        int w = (t >= off) ? sc[t - off] : 0;
        __syncthreads();
        sc[t] += w;
        __syncthreads();
    }
    if (t < K) cbase[t] = sc[t] - v;
    if (t == 0) { cbase[K] = E; offsets[N] = E; *spill_cursor = 0; }
}

__global__ void __launch_bounds__(NBLK) chunk_base_kernel(
        const int* __restrict__ cnt, const int* __restrict__ cbase,
        int* __restrict__ base_tab) {
    __shared__ int sc[NBLK];
    int b = blockIdx.x;
    int t = threadIdx.x;
    int v = cnt[b * NBLK + t];
    sc[t] = v;
    __syncthreads();
    for (int off = 1; off < NBLK; off <<= 1) {
        int w = (t >= off) ? sc[t - off] : 0;
        __syncthreads();
        sc[t] += w;
        __syncthreads();
    }
    base_tab[b * NBLK + t] = cbase[b] + sc[t] - v;
}

__global__ void __launch_bounds__(1024) coarse_scatter_kernel(
        const int* __restrict__ dst, const int* __restrict__ src,
        const float4* __restrict__ sh, const int* __restrict__ base_tab,
        uint2* __restrict__ pay8, int* __restrict__ packed,
        int E, int K, int EPB) {
    __shared__ int cur[MAXK];
    for (int b = threadIdx.x; b < K; b += 1024)
        cur[b] = base_tab[b * NBLK + blockIdx.x];
    __syncthreads();
    int base = blockIdx.x * EPB;
    int lim = min(EPB, E - base);
    for (int i = threadIdx.x; i < lim; i += 1024) {
        int e = base + i;
        int d = dst[e];
        int b = d >> LOG_NPBK;
        int pos = atomicAdd(&cur[b], 1);
        float4 s4 = sh[e];
        pay8[pos] = make_uint2(f2bf(s4.x) | (f2bf(s4.y) << 16),
                               f2bf(s4.z) | (f2bf(s4.w) << 16));
        packed[pos] = ((d & (NPBK - 1)) << 24) | src[e];
    }
}

__global__ void __launch_bounds__(512) fine_sort_kernel(
        const int* __restrict__ cbase, int* __restrict__ offsets,
        uint2* __restrict__ pay8, int* __restrict__ packed,
        uint2* __restrict__ spill_pay, int* __restrict__ spill_pk,
        int* __restrict__ spill_cursor, int N) {
    __shared__ uint2 spay[CAP];
    __shared__ int   spk[CAP];
    __shared__ int   cnt_[NPBK];
    __shared__ int   sc[NPBK];
    __shared__ int   sbase_s;
    int b = blockIdx.x;
    int t = threadIdx.x;
    int cbeg = cbase[b], cend = cbase[b + 1];
    int cnt = cend - cbeg;
    if (t == 0) sbase_s = (cnt > CAP) ? atomicAdd(spill_cursor, cnt - CAP) : 0;
    if (t < NPBK) cnt_[t] = 0;
    __syncthreads();
    for (int i = t; i < cnt; i += 512) {
        int pk = packed[cbeg + i];
        uint2 p8 = pay8[cbeg + i];
        atomicAdd(&cnt_[(pk >> 24) & (NPBK - 1)], 1);
        if (i < CAP) { spk[i] = pk; spay[i] = p8; }
        else {
            int sp = sbase_s + (i - CAP);
            if (sp < SPILL_E) { spill_pk[sp] = pk; spill_pay[sp] = p8; }
        }
    }
    __syncthreads();
    int v = (t < NPBK) ? cnt_[t] : 0;
    if (t < NPBK) sc[t] = v;
    __syncthreads();
    for (int off = 1; off < NPBK; off <<= 1) {
        int w = (t < NPBK && t >= off) ? sc[t - off] : 0;
        __syncthreads();
        if (t < NPBK) sc[t] += w;
        __syncthreads();
    }
    if (t < NPBK) {
        int ex = sc[t] - v;
        int node = (b << LOG_NPBK) + t;
        if (node <= N) offsets[node] = cbeg + ex;
        cnt_[t] = ex;
    }
    __syncthreads();
    for (int i = t; i < cnt; i += 512) {
        int pk; uint2 p8;
        bool ok = true;
        if (i < CAP) { pk = spk[i]; p8 = spay[i]; }
        else {
            int sp = sbase_s + (i - CAP);
            ok = (sp < SPILL_E);
            if (ok) { pk = spill_pk[sp]; p8 = spill_pay[sp]; }
        }
        if (ok) {
            int pos = cbeg + atomicAdd(&cnt_[(pk >> 24) & (NPBK - 1)], 1);
            packed[pos] = pk;
            pay8[pos] = p8;
        }
    }
}

// --- Fallback tiers 3/4 ---
constexpr int SCAN_BLOCK = 256;
constexpr int SCAN_ITEMS = 8;
constexpr int SCAN_CHUNK = SCAN_BLOCK * SCAN_ITEMS;

__global__ void __launch_bounds__(256) hist_kernel(
        const int* __restrict__ dst, int* __restrict__ counts, int E) {
    int e = blockIdx.x * blockDim.x + threadIdx.x;
    if (e < E) atomicAdd(&counts[dst[e]], 1);
}
__global__ void __launch_bounds__(SCAN_BLOCK) block_sum_kernel(
        const int* __restrict__ counts, int* __restrict__ bsums, int N) {
    __shared__ int sdata[SCAN_BLOCK];
    int base = blockIdx.x * SCAN_CHUNK;
    int sum = 0;
    for (int j = 0; j < SCAN_ITEMS; ++j) {
        int idx = base + j * SCAN_BLOCK + threadIdx.x;
        if (idx < N) sum += counts[idx];
    }
    sdata[threadIdx.x] = sum;
    __syncthreads();
    for (int off = SCAN_BLOCK / 2; off > 0; off >>= 1) {
        if (threadIdx.x < off) sdata[threadIdx.x] += sdata[threadIdx.x + off];
        __syncthreads();
    }
    if (threadIdx.x == 0) bsums[blockIdx.x] = sdata[0];
}
__global__ void scan_bsums_kernel(int* __restrict__ bsums, int nb) {
    if (threadIdx.x == 0 && blockIdx.x == 0) {
        int acc = 0;
        for (int i = 0; i < nb; ++i) { int v = bsums[i]; bsums[i] = acc; acc += v; }
    }
}
__global__ void __launch_bounds__(SCAN_BLOCK) scan_final_kernel(
        const int* __restrict__ counts, const int* __restrict__ bsums,
        int* __restrict__ offsets, int* __restrict__ cursors, int N, int E) {
    __shared__ int sdata[SCAN_BLOCK];
    int base = blockIdx.x * SCAN_CHUNK + threadIdx.x * SCAN_ITEMS;
    int local[SCAN_ITEMS];
    int tsum = 0;
    for (int j = 0; j < SCAN_ITEMS; ++j) {
        int idx = base + j;
        int v = (idx < N) ? counts[idx] : 0;
        local[j] = tsum;
        tsum += v;
    }
    sdata[threadIdx.x] = tsum;
    __syncthreads();
    for (int off = 1; off < SCAN_BLOCK; off <<= 1) {
        int v = (threadIdx.x >= off) ? sdata[threadIdx.x - off] : 0;
        __syncthreads();
        sdata[threadIdx.x] += v;
        __syncthreads();
    }
    int excl = sdata[threadIdx.x] - tsum + bsums[blockIdx.x];
    for (int j = 0; j < SCAN_ITEMS; ++j) {
        int idx = base + j;
        if (idx < N) { int o = excl + local[j]; offsets[idx] = o; cursors[idx] = o; }
    }
    if (blockIdx.x == 0 && threadIdx.x == 0) offsets[N] = E;
}
__global__ void __launch_bounds__(256) scatter_ids_kernel(
        const int* __restrict__ dst, int* __restrict__ cursors,
        int* __restrict__ eids, int E) {
    int e = blockIdx.x * blockDim.x + threadIdx.x;
    if (e < E) { int pos = atomicAdd(&cursors[dst[e]], 1); eids[pos] = e; }
}
__global__ void __launch_bounds__(US) accum_ids_kernel(
        const float* __restrict__ x, const float* __restrict__ sh,
        const int* __restrict__ src, const int* __restrict__ offsets,
        const int* __restrict__ eids, float* __restrict__ out) {
    int n = blockIdx.x;
    int t = threadIdx.x;
    int u = t >> 2, s = t & 3;
    int beg = offsets[n], end = offsets[n + 1];
    float acc = 0.f;
    for (int i = beg; i < end; ++i) {
        int e = eids[i];
        acc += x[src[e] * U_DIM + u] * sh[e * 4 + s];
    }
    out[(size_t)n * US + t] = acc;
}
__global__ void __launch_bounds__(US) atomic_kernel(
        const float* __restrict__ x, const float* __restrict__ sh,
        const int* __restrict__ src, const int* __restrict__ dst,
        float* __restrict__ out, int E) {
    int e = blockIdx.x;
    int t = threadIdx.x;
    float v = x[src[e] * U_DIM + (t >> 2)] * sh[e * 4 + (t & 3)];
    atomicAdd(&out[(size_t)dst[e] * US + t], v);
}

extern "C" void kernel_launch(void* const* d_in, const int* in_sizes, int n_in,
                              void* d_out, int out_size, void* d_ws, size_t ws_size,
                              hipStream_t stream) {
    const float* x  = (const float*)d_in[0];
    const float* sh = (const float*)d_in[1];
    const int* src  = (const int*)d_in[2];
    const int* dst  = (const int*)d_in[3];
    float* out = (float*)d_out;

    const int E = in_sizes[2];
    const int N = in_sizes[0] / U_DIM;
    const int xn4 = in_sizes[0] / 4;
    const int egrid = (E + 255) / 256;
    const int nb = (N + SCAN_CHUNK - 1) / SCAN_CHUNK;

    const int K1 = (N + C1_NPB - 1) >> C1_LOG;
    const int KF = (N + FINE_NPB - 1) >> FINE_LOG;
    const int EPB1 = (E + C1_NBLK - 1) / C1_NBLK;
    size_t need_main = (size_t)E * 24 + (size_t)in_sizes[0] * 2 +
                       (size_t)(N + 1 + 2 * KF + 2 + K1 + 1 +
                                2 * K1 * C1_NBLK) * 4;

    const int K = (N + NPBK - 1) >> LOG_NPBK;
    const int EPB = (E + NBLK - 1) / NBLK;
    size_t need_r7 = (size_t)E * 12 + (size_t)SPILL_E * 12 + (size_t)(N + 1) * 4 +
                     (size_t)(2 * K + 2) * 4 + (size_t)(2 * K * NBLK) * 4 +
                     (size_t)in_sizes[0] * 2;
    size_t need_ids = (size_t)E * 4 + (size_t)(3 * N + 1 + nb) * 4;

    if (K1 <= C1_MAXK && KF <= KF_MAX && N <= (1 << 21) &&
        (in_sizes[0] % 4 == 0) && ws_size >= need_main) {
        uint2* pay8A   = (uint2*)d_ws;
        uint2* pay8B   = pay8A + E;
        int* packedA   = (int*)(pay8B + E);
        int* packedB   = packedA + E;
        unsigned short* xb = (unsigned short*)(packedB + E);
        int* offsets   = (int*)(xb + in_sizes[0]);
        int* ccount_f  = offsets + N + 1;
        int* fbase     = ccount_f + KF;
        int* cbase     = fbase + KF + 1;
        int* cnt       = cbase + K1 + 1;
        int* base_tab  = cnt + K1 * C1_NBLK;

        hipMemsetAsync(ccount_f, 0, sizeof(int) * (size_t)KF, stream);
        xcvt_kernel<<<(xn4 + 255) / 256, 256, 0, stream>>>(
            (const float4*)x, (ushort4*)xb, xn4);
        c1_hist_kernel<<<C1_NBLK, 1024, 0, stream>>>(dst, ccount_f, cnt,
                                                     E, KF, K1, EPB1);
        c1_scan_kernel<<<1, 1024, 0, stream>>>(ccount_f, fbase, cbase, offsets,
                                               KF, K1, N, E);
        c1_cbase_kernel<<<K1, C1_NBLK, 0, stream>>>(cnt, cbase, base_tab);
        c1_scatter_kernel<<<C1_NBLK, 1024, 0, stream>>>(dst, src, (const float4*)sh,
                                                        base_tab, pay8A, packedA,
                                                        E, K1, EPB1);
        c2_sort_kernel<<<KF, 1024, 0, stream>>>(cbase, fbase, offsets,
                                                pay8A, packedA, pay8B, packedB, N);
        accum_kernel<<<(N + 15) / 16, 256, 0, stream>>>(xb, pay8B, packedB,
                                                        offsets, out, 0x1FFFFF, N);
    } else if (K <= MAXK && (in_sizes[0] % 4 == 0) && ws_size >= need_r7) {
        uint2* pay8      = (uint2*)d_ws;
        uint2* spill_pay = pay8 + E;
        int* packed      = (int*)(spill_pay + SPILL_E);
        int* spill_pk    = packed + E;
        int* offsets     = spill_pk + SPILL_E;
        int* ccount      = offsets + N + 1;
        int* cbase       = ccount + K;
        int* cnt         = cbase + K + 1;
        int* base_tab    = cnt + K * NBLK;
        int* spill_cur   = base_tab + K * NBLK;
        unsigned short* xb = (unsigned short*)(spill_cur + 1);

        hipMemsetAsync(ccount, 0, sizeof(int) * (size_t)K, stream);
        xcvt_kernel<<<(xn4 + 255) / 256, 256, 0, stream>>>(
            (const float4*)x, (ushort4*)xb, xn4);
        coarse_hist_kernel<<<NBLK, 1024, 0, stream>>>(dst, ccount, cnt, E, K, EPB);
        coarse_scan_kernel<<<1, 1024, 0, stream>>>(ccount, cbase, offsets,
                                                   spill_cur, K, N, E);
        chunk_base_kernel<<<K, NBLK, 0, stream>>>(cnt, cbase, base_tab);
        coarse_scatter_kernel<<<NBLK, 1024, 0, stream>>>(dst, src, (const float4*)sh,
                                                         base_tab, pay8, packed,
                                                         E, K, EPB);
        fine_sort_kernel<<<K, 512, 0, stream>>>(cbase, offsets, pay8, packed,
                                                spill_pay, spill_pk, spill_cur, N);
        accum_kernel<<<(N + 15) / 16, 256, 0, stream>>>(xb, pay8, packed,
                                                        offsets, out, 0xFFFFFF, N);
    } else if (ws_size >= need_ids) {
        int* eids    = (int*)d_ws;
        int* counts  = eids + E;
        int* offsets = counts + N;
        int* cursors = offsets + N + 1;
        int* bsums   = cursors + N;

        hipMemsetAsync(counts, 0, sizeof(int) * (size_t)N, stream);
        hist_kernel<<<egrid, 256, 0, stream>>>(dst, counts, E);
        block_sum_kernel<<<nb, SCAN_BLOCK, 0, stream>>>(counts, bsums, N);
        scan_bsums_kernel<<<1, 64, 0, stream>>>(bsums, nb);
        scan_final_kernel<<<nb, SCAN_BLOCK, 0, stream>>>(counts, bsums, offsets, cursors, N, E);
        scatter_ids_kernel<<<egrid, 256, 0, stream>>>(dst, cursors, eids, E);
        accum_ids_kernel<<<N, US, 0, stream>>>(x, sh, src, offsets, eids, out);
    } else {
        hipMemsetAsync(out, 0, sizeof(float) * (size_t)out_size, stream);
        atomic_kernel<<<E, US, 0, stream>>>(x, sh, src, dst, out, E);
    }
}

// Round 20
// 186.527 us; speedup vs baseline: 1.0565x; 1.0058x over previous
//
#include <hip/hip_runtime.h>

// out[n, u*4+s] = sum_{e: dst[e]==n} x[src[e], u] * sh[e, s]
// N=100000, U=32, S=4, E=3200000.
//
// Ledger of lessons:
//  R2: bulk LDS float atomics / single-counter atomics = serial floor.
//  R4/R5/R7: scattered writes, many streams/block = HBM write amp.
//  R8: few deep-serial blocks lose to many shallow blocks.
//  R9/R13: xb/sh are L3-resident; FETCH is L2-fill traffic.
//  R10: NT loads on shared streams re-fetch lines.
//  R11/R15/R16: accum: contiguous ranges, nodes-per-wave widening with ZERO
//      cross-lane reduction is the winning axis (99->87->65->62us).
//  R12: lane-widening WITH cross-lane reduction = loss.
//  R13: XCD-swizzle on undefined block->XCD mapping: reverted.
//  R17: c1 subchunk LDS-sort + burst write kills write amp.
//  R18/R19: c2 single-read + 1024 threads (32 waves/CU): off top-5.
// R20: accum 8 nodes/wave (grp=lane>>3, ushort4 x-load, acc[16]/lane,
//      16 contiguous output floats/lane). VMEM issues per edge halved.

#define U_DIM 32
#define US 128

__device__ inline unsigned f2bf(float f) {          // RNE float->bf16 bits
    unsigned u = __float_as_uint(f);
    return (u + 0x7FFF + ((u >> 16) & 1)) >> 16;
}
__device__ inline float bfl(unsigned w) { return __uint_as_float(w << 16); }
__device__ inline float bfh(unsigned w) { return __uint_as_float(w & 0xFFFF0000u); }

__global__ void __launch_bounds__(256) xcvt_kernel(
        const float4* __restrict__ x4, ushort4* __restrict__ xb4, int n4) {
    int i = blockIdx.x * 256 + threadIdx.x;
    if (i < n4) {
        float4 v = x4[i];
        ushort4 r;
        r.x = (unsigned short)f2bf(v.x);
        r.y = (unsigned short)f2bf(v.y);
        r.z = (unsigned short)f2bf(v.z);
        r.w = (unsigned short)f2bf(v.w);
        xb4[i] = r;
    }
}

// =================== PRIMARY PATH ===================
#define C1_LOG 9
#define C1_NPB 512
#define C1_MAXK 256
#define C1_NBLK 256
#define FINE_LOG 7
#define FINE_NPB 128
#define KF_MAX 1024
#define SCAP 5120             // LDS-staged edges per fine bucket (mean 4082)
#define SCH 4096              // c1_scatter subchunk (LDS-sorted burst unit)

// Fine-granularity (128-node) histogram; also per-chunk coarse counts.
__global__ void __launch_bounds__(1024) c1_hist_kernel(
        const int* __restrict__ dst, int* __restrict__ ccount_f,
        int* __restrict__ cnt, int E, int KF, int K1, int EPB) {
    __shared__ int h[KF_MAX];
    for (int b = threadIdx.x; b < KF; b += 1024) h[b] = 0;
    __syncthreads();
    int base = blockIdx.x * EPB;
    int lim = min(EPB, E - base);
    for (int i = threadIdx.x; i < lim; i += 1024)
        atomicAdd(&h[dst[base + i] >> FINE_LOG], 1);
    __syncthreads();
    for (int b = threadIdx.x; b < KF; b += 1024) {
        int c = h[b];
        if (c) atomicAdd(&ccount_f[b], c);
    }
    for (int b = threadIdx.x; b < K1; b += 1024) {
        int c = 0;
        #pragma unroll
        for (int k = 0; k < 4; ++k) {
            int f = 4 * b + k;
            if (f < KF) c += h[f];
        }
        cnt[b * C1_NBLK + blockIdx.x] = c;
    }
}

// One scan over KF fine counts -> fbase; cbase derived; offsets[N]=E.
__global__ void __launch_bounds__(1024) c1_scan_kernel(
        const int* __restrict__ ccount_f, int* __restrict__ fbase,
        int* __restrict__ cbase, int* __restrict__ offsets,
        int KF, int K1, int N, int E) {
    __shared__ int sc[1024];
    int t = threadIdx.x;
    int v = (t < KF) ? ccount_f[t] : 0;
    sc[t] = v;
    __syncthreads();
    for (int off = 1; off < 1024; off <<= 1) {
        int w = (t >= off) ? sc[t - off] : 0;
        __syncthreads();
        sc[t] += w;
        __syncthreads();
    }
    if (t < KF) fbase[t] = sc[t] - v;
    __syncthreads();
    if (t < K1) {
        int f = 4 * t;
        cbase[t] = (f < KF) ? (sc[f] - ccount_f[f]) : E;
    }
    if (t == 0) { fbase[KF] = E; cbase[K1] = E; offsets[N] = E; }
}

__global__ void __launch_bounds__(C1_NBLK) c1_cbase_kernel(
        const int* __restrict__ cnt, const int* __restrict__ cbase,
        int* __restrict__ base_tab) {
    __shared__ int sc[C1_NBLK];
    int b = blockIdx.x;
    int t = threadIdx.x;
    int v = cnt[b * C1_NBLK + t];
    sc[t] = v;
    __syncthreads();
    for (int off = 1; off < C1_NBLK; off <<= 1) {
        int w = (t >= off) ? sc[t - off] : 0;
        __syncthreads();
        sc[t] += w;
        __syncthreads();
    }
    base_tab[b * C1_NBLK + t] = cbase[b] + sc[t] - v;
}

// R17: subchunk LDS counting-sort + burst write. Writes for each output line
// arrive back-to-back from consecutive lanes -> L2 write-combining succeeds.
__global__ void __launch_bounds__(1024) c1_scatter_kernel(
        const int* __restrict__ dst, const int* __restrict__ src,
        const float4* __restrict__ sh, const int* __restrict__ base_tab,
        uint2* __restrict__ pay8A, int* __restrict__ packedA,
        int E, int K1, int EPB) {
    __shared__ uint2 spay[SCH];           // 32 KB
    __shared__ int   spk[SCH];            // 16 KB
    __shared__ unsigned char sbkt[SCH];   // 4 KB
    __shared__ int   hist[C1_MAXK];
    __shared__ int   lo[C1_MAXK];
    __shared__ int   scur[C1_MAXK];
    __shared__ int   gcur[C1_MAXK];
    __shared__ int   sc[C1_MAXK];
    int t = threadIdx.x;
    for (int b = t; b < K1; b += 1024)
        gcur[b] = base_tab[b * C1_NBLK + blockIdx.x];
    int base = blockIdx.x * EPB;
    int lim = min(EPB, E - base);

    for (int sb = 0; sb < lim; sb += SCH) {
        int sublen = min(SCH, lim - sb);
        for (int b = t; b < K1; b += 1024) hist[b] = 0;
        __syncthreads();
        int bk[4], pk[4];
        uint2 pv[4];
        bool vld[4];
        #pragma unroll
        for (int k = 0; k < 4; ++k) {
            int idx = t + k * 1024;
            vld[k] = (idx < sublen);
            if (vld[k]) {
                int e = base + sb + idx;
                int d = dst[e];
                bk[k] = d >> C1_LOG;
                float4 s4 = sh[e];
                pv[k] = make_uint2(f2bf(s4.x) | (f2bf(s4.y) << 16),
                                   f2bf(s4.z) | (f2bf(s4.w) << 16));
                pk[k] = ((d & (C1_NPB - 1)) << 21) | src[e];
                atomicAdd(&hist[bk[k]], 1);
            }
        }
        __syncthreads();
        if (t < C1_MAXK) sc[t] = (t < K1) ? hist[t] : 0;
        __syncthreads();
        for (int off = 1; off < C1_MAXK; off <<= 1) {
            int w = 0;
            if (t < C1_MAXK && t >= off) w = sc[t - off];
            __syncthreads();
            if (t < C1_MAXK) sc[t] += w;
            __syncthreads();
        }
        if (t < C1_MAXK) {
            int excl = sc[t] - ((t < K1) ? hist[t] : 0);
            lo[t] = excl;
            scur[t] = excl;
        }
        __syncthreads();
        #pragma unroll
        for (int k = 0; k < 4; ++k) {
            if (vld[k]) {
                int pos = atomicAdd(&scur[bk[k]], 1);
                spk[pos] = pk[k];
                spay[pos] = pv[k];
                sbkt[pos] = (unsigned char)bk[k];
            }
        }
        __syncthreads();
        for (int i = t; i < sublen; i += 1024) {
            int b = sbkt[i];
            int gd = gcur[b] + (i - lo[b]);
            packedA[gd] = spk[i];
            pay8A[gd] = spay[i];
        }
        __syncthreads();
        if (t < K1) gcur[t] += hist[t];
        __syncthreads();
    }
}

// R19: one block per fine bucket, 1024 threads (2 blk/CU x 1024 = 32 waves/CU).
// Single read of parent range; matching edges staged UNSORTED in LDS (wave-
// aggregated ballot reservation), then placed LDS->global sorted.
__global__ void __launch_bounds__(1024) c2_sort_kernel(
        const int* __restrict__ cbase, const int* __restrict__ fbase,
        int* __restrict__ offsets, const uint2* __restrict__ pay8A,
        const int* __restrict__ packedA, uint2* __restrict__ pay8B,
        int* __restrict__ packedB, int N) {
    __shared__ uint2 spay[SCAP];          // 40 KB
    __shared__ int   spk[SCAP];           // 20 KB
    __shared__ int   hh[FINE_NPB];
    __shared__ int   scur[FINE_NPB];
    __shared__ int   stot;
    int fb = blockIdx.x;
    int t = threadIdx.x;
    int lane = t & 63;
    int parent = fb >> 2, sub = fb & 3;
    int cbeg = cbase[parent], cend = cbase[parent + 1];
    int fbeg = fbase[fb];
    int cnt = fbase[fb + 1] - fbeg;
    if (t < FINE_NPB) hh[t] = 0;
    if (t == 0) stot = 0;
    __syncthreads();

    if (cnt <= SCAP) {
        for (int i = cbeg + t; i < cend; i += 1024) {
            int pk = packedA[i];
            int nc = (pk >> 21) & (C1_NPB - 1);
            bool m = ((nc >> FINE_LOG) == sub);
            unsigned long long mask = __ballot(m);
            if (m) {
                atomicAdd(&hh[nc & (FINE_NPB - 1)], 1);
                int leader = __ffsll((long long)mask) - 1;
                int base_ = 0;
                if (lane == leader) base_ = atomicAdd(&stot, __popcll(mask));
                base_ = __shfl(base_, leader);
                int pos = base_ + __popcll(mask & ((1ull << lane) - 1ull));
                spk[pos] = pk;
                spay[pos] = pay8A[i];
            }
        }
        __syncthreads();
        int v = (t < FINE_NPB) ? hh[t] : 0;
        if (t < FINE_NPB) hh[t] = v;
        __syncthreads();
        for (int off = 1; off < FINE_NPB; off <<= 1) {
            int w = (t < FINE_NPB && t >= off) ? hh[t - off] : 0;
            __syncthreads();
            if (t < FINE_NPB) hh[t] += w;
            __syncthreads();
        }
        if (t < FINE_NPB) {
            int excl = hh[t] - v;
            scur[t] = fbeg + excl;
            int node = (fb << FINE_LOG) + t;
            if (node < N) offsets[node] = fbeg + excl;
        }
        __syncthreads();
        for (int j = t; j < cnt; j += 1024) {
            int pk = spk[j];
            int node = (pk >> 21) & (FINE_NPB - 1);
            int pos = atomicAdd(&scur[node], 1);
            packedB[pos] = pk;
            pay8B[pos] = spay[j];
        }
    } else {
        for (int i = cbeg + t; i < cend; i += 1024) {
            int nc = (packedA[i] >> 21) & (C1_NPB - 1);
            if ((nc >> FINE_LOG) == sub)
                atomicAdd(&hh[nc & (FINE_NPB - 1)], 1);
        }
        __syncthreads();
        int v = (t < FINE_NPB) ? hh[t] : 0;
        if (t < FINE_NPB) hh[t] = v;
        __syncthreads();
        for (int off = 1; off < FINE_NPB; off <<= 1) {
            int w = (t < FINE_NPB && t >= off) ? hh[t - off] : 0;
            __syncthreads();
            if (t < FINE_NPB) hh[t] += w;
            __syncthreads();
        }
        if (t < FINE_NPB) {
            int excl = hh[t] - v;
            scur[t] = fbeg + excl;
            int node = (fb << FINE_LOG) + t;
            if (node < N) offsets[node] = fbeg + excl;
        }
        __syncthreads();
        for (int i = cbeg + t; i < cend; i += 1024) {
            int pk = packedA[i];
            int nc = (pk >> 21) & (C1_NPB - 1);
            if ((nc >> FINE_LOG) == sub) {
                int pos = atomicAdd(&scur[nc & (FINE_NPB - 1)], 1);
                packedB[pos] = pk;
                pay8B[pos] = pay8A[i];
            }
        }
    }
}

// R20 accum: 256-thr block = 4 waves; each wave handles 8 nodes (grp=lane>>3).
// Lane l=lane&7 covers u={4l..4l+3} via one ushort4 x-load. Per edge: 8-lane
// group broadcast-loads payload, 16 FMAs into acc[16]. NO reduction, NO LDS:
// each lane stores its 16 contiguous output floats directly. Unroll-4 MLP.
__global__ void __launch_bounds__(256) accum_kernel(
        const unsigned short* __restrict__ xb, const uint2* __restrict__ pay8,
        const int* __restrict__ packed, const int* __restrict__ offsets,
        float* __restrict__ out, int smask, int N) {
    int wave = threadIdx.x >> 6;
    int lane = threadIdx.x & 63;
    int grp = lane >> 3;              // 0..7 node within wave
    int l = lane & 7;                 // covers u = 4l .. 4l+3
    int n = blockIdx.x * 32 + wave * 8 + grp;
    if (n >= N) return;
    int beg = offsets[n], end = offsets[n + 1];
    int u4 = l << 2;
    float acc[16];
    #pragma unroll
    for (int j = 0; j < 16; ++j) acc[j] = 0.f;

    int i = beg;
    for (; i + 3 < end; i += 4) {
        int pk0 = packed[i], pk1 = packed[i + 1];
        int pk2 = packed[i + 2], pk3 = packed[i + 3];
        uint2 q0 = pay8[i], q1 = pay8[i + 1];
        uint2 q2 = pay8[i + 2], q3 = pay8[i + 3];
        ushort4 xv0 = *reinterpret_cast<const ushort4*>(
            &xb[(size_t)(pk0 & smask) * U_DIM + u4]);
        ushort4 xv1 = *reinterpret_cast<const ushort4*>(
            &xb[(size_t)(pk1 & smask) * U_DIM + u4]);
        ushort4 xv2 = *reinterpret_cast<const ushort4*>(
            &xb[(size_t)(pk2 & smask) * U_DIM + u4]);
        ushort4 xv3 = *reinterpret_cast<const ushort4*>(
            &xb[(size_t)(pk3 & smask) * U_DIM + u4]);
        {
            float s0 = bfl(q0.x), s1 = bfh(q0.x), s2 = bfl(q0.y), s3 = bfh(q0.y);
            float xa = bfl((unsigned)xv0.x), xbv = bfl((unsigned)xv0.y);
            float xc = bfl((unsigned)xv0.z), xd = bfl((unsigned)xv0.w);
            acc[0]  += xa * s0; acc[1]  += xa * s1; acc[2]  += xa * s2; acc[3]  += xa * s3;
            acc[4]  += xbv * s0; acc[5]  += xbv * s1; acc[6]  += xbv * s2; acc[7]  += xbv * s3;
            acc[8]  += xc * s0; acc[9]  += xc * s1; acc[10] += xc * s2; acc[11] += xc * s3;
            acc[12] += xd * s0; acc[13] += xd * s1; acc[14] += xd * s2; acc[15] += xd * s3;
        }
        {
            float s0 = bfl(q1.x), s1 = bfh(q1.x), s2 = bfl(q1.y), s3 = bfh(q1.y);
            float xa = bfl((unsigned)xv1.x), xbv = bfl((unsigned)xv1.y);
            float xc = bfl((unsigned)xv1.z), xd = bfl((unsigned)xv1.w);
            acc[0]  += xa * s0; acc[1]  += xa * s1; acc[2]  += xa * s2; acc[3]  += xa * s3;
            acc[4]  += xbv * s0; acc[5]  += xbv * s1; acc[6]  += xbv * s2; acc[7]  += xbv * s3;
            acc[8]  += xc * s0; acc[9]  += xc * s1; acc[10] += xc * s2; acc[11] += xc * s3;
            acc[12] += xd * s0; acc[13] += xd * s1; acc[14] += xd * s2; acc[15] += xd * s3;
        }
        {
            float s0 = bfl(q2.x), s1 = bfh(q2.x), s2 = bfl(q2.y), s3 = bfh(q2.y);
            float xa = bfl((unsigned)xv2.x), xbv = bfl((unsigned)xv2.y);
            float xc = bfl((unsigned)xv2.z), xd = bfl((unsigned)xv2.w);
            acc[0]  += xa * s0; acc[1]  += xa * s1; acc[2]  += xa * s2; acc[3]  += xa * s3;
            acc[4]  += xbv * s0; acc[5]  += xbv * s1; acc[6]  += xbv * s2; acc[7]  += xbv * s3;
            acc[8]  += xc * s0; acc[9]  += xc * s1; acc[10] += xc * s2; acc[11] += xc * s3;
            acc[12] += xd * s0; acc[13] += xd * s1; acc[14] += xd * s2; acc[15] += xd * s3;
        }
        {
            float s0 = bfl(q3.x), s1 = bfh(q3.x), s2 = bfl(q3.y), s3 = bfh(q3.y);
            float xa = bfl((unsigned)xv3.x), xbv = bfl((unsigned)xv3.y);
            float xc = bfl((unsigned)xv3.z), xd = bfl((unsigned)xv3.w);
            acc[0]  += xa * s0; acc[1]  += xa * s1; acc[2]  += xa * s2; acc[3]  += xa * s3;
            acc[4]  += xbv * s0; acc[5]  += xbv * s1; acc[6]  += xbv * s2; acc[7]  += xbv * s3;
            acc[8]  += xc * s0; acc[9]  += xc * s1; acc[10] += xc * s2; acc[11] += xc * s3;
            acc[12] += xd * s0; acc[13] += xd * s1; acc[14] += xd * s2; acc[15] += xd * s3;
        }
    }
    for (; i < end; ++i) {
        int pk = packed[i];
        uint2 q = pay8[i];
        ushort4 xv = *reinterpret_cast<const ushort4*>(
            &xb[(size_t)(pk & smask) * U_DIM + u4]);
        float s0 = bfl(q.x), s1 = bfh(q.x), s2 = bfl(q.y), s3 = bfh(q.y);
        float xa = bfl((unsigned)xv.x), xbv = bfl((unsigned)xv.y);
        float xc = bfl((unsigned)xv.z), xd = bfl((unsigned)xv.w);
        acc[0]  += xa * s0; acc[1]  += xa * s1; acc[2]  += xa * s2; acc[3]  += xa * s3;
        acc[4]  += xbv * s0; acc[5]  += xbv * s1; acc[6]  += xbv * s2; acc[7]  += xbv * s3;
        acc[8]  += xc * s0; acc[9]  += xc * s1; acc[10] += xc * s2; acc[11] += xc * s3;
        acc[12] += xd * s0; acc[13] += xd * s1; acc[14] += xd * s2; acc[15] += xd * s3;
    }
    size_t obase = (size_t)n * US + (size_t)u4 * 4;
    #pragma unroll
    for (int jj = 0; jj < 4; ++jj) {
        *reinterpret_cast<float4*>(&out[obase + jj * 4]) =
            make_float4(acc[jj * 4 + 0], acc[jj * 4 + 1],
                        acc[jj * 4 + 2], acc[jj * 4 + 3]);
    }
}

// =================== TIER-2: proven R7 path ===================
#define LOG_NPBK 7
#define NPBK 128
#define MAXK 1024
#define NBLK 256
#define CAP 5120
#define SPILL_E 1000000

__global__ void __launch_bounds__(1024) coarse_hist_kernel(
        const int* __restrict__ dst, int* __restrict__ ccount,
        int* __restrict__ cnt, int E, int K, int EPB) {
    __shared__ int h[MAXK];
    for (int b = threadIdx.x; b < K; b += 1024) h[b] = 0;
    __syncthreads();
    int base = blockIdx.x * EPB;
    int lim = min(EPB, E - base);
    for (int i = threadIdx.x; i < lim; i += 1024)
        atomicAdd(&h[dst[base + i] >> LOG_NPBK], 1);
    __syncthreads();
    for (int b = threadIdx.x; b < K; b += 1024) {
        int c = h[b];
        cnt[b * NBLK + blockIdx.x] = c;
        if (c) atomicAdd(&ccount[b], c);
    }
}

__global__ void __launch_bounds__(1024) coarse_scan_kernel(
        const int* __restrict__ ccount, int* __restrict__ cbase,
        int* __restrict__ offsets, int* __restrict__ spill_cursor,
        int K, int N, int E) {
    __shared__ int sc[1024];
    int t = threadIdx.x;
    int v = (t < K) ? ccount[t] : 0;
    sc[t] = v;
    __syncthreads();
    for (int off = 1; off < 1024; off <<= 1) {
        int w = (t >= off) ? sc[t - off] : 0;
        __syncthreads();
        sc[t] += w;
        __syncthreads();
    }
    if (t < K) cbase[t] = sc[t] - v;
    if (t == 0) { cbase[K] = E; offsets[N] = E; *spill_cursor = 0; }
}

__global__ void __launch_bounds__(NBLK) chunk_base_kernel(
        const int* __restrict__ cnt, const int* __restrict__ cbase,
        int* __restrict__ base_tab) {
    __shared__ int sc[NBLK];
    int b = blockIdx.x;
    int t = threadIdx.x;
    int v = cnt[b * NBLK + t];
    sc[t] = v;
    __syncthreads();
    for (int off = 1; off < NBLK; off <<= 1) {
        int w = (t >= off) ? sc[t - off] : 0;
        __syncthreads();
        sc[t] += w;
        __syncthreads();
    }
    base_tab[b * NBLK + t] = cbase[b] + sc[t] - v;
}

__global__ void __launch_bounds__(1024) coarse_scatter_kernel(
        const int* __restrict__ dst, const int* __restrict__ src,
        const float4* __restrict__ sh, const int* __restrict__ base_tab,
        uint2* __restrict__ pay8, int* __restrict__ packed,
        int E, int K, int EPB) {
    __shared__ int cur[MAXK];
    for (int b = threadIdx.x; b < K; b += 1024)
        cur[b] = base_tab[b * NBLK + blockIdx.x];
    __syncthreads();
    int base = blockIdx.x * EPB;
    int lim = min(EPB, E - base);
    for (int i = threadIdx.x; i < lim; i += 1024) {
        int e = base + i;
        int d = dst[e];
        int b = d >> LOG_NPBK;
        int pos = atomicAdd(&cur[b], 1);
        float4 s4 = sh[e];
        pay8[pos] = make_uint2(f2bf(s4.x) | (f2bf(s4.y) << 16),
                               f2bf(s4.z) | (f2bf(s4.w) << 16));
        packed[pos] = ((d & (NPBK - 1)) << 24) | src[e];
    }
}

__global__ void __launch_bounds__(512) fine_sort_kernel(
        const int* __restrict__ cbase, int* __restrict__ offsets,
        uint2* __restrict__ pay8, int* __restrict__ packed,
        uint2* __restrict__ spill_pay, int* __restrict__ spill_pk,
        int* __restrict__ spill_cursor, int N) {
    __shared__ uint2 spay[CAP];
    __shared__ int   spk[CAP];
    __shared__ int   cnt_[NPBK];
    __shared__ int   sc[NPBK];
    __shared__ int   sbase_s;
    int b = blockIdx.x;
    int t = threadIdx.x;
    int cbeg = cbase[b], cend = cbase[b + 1];
    int cnt = cend - cbeg;
    if (t == 0) sbase_s = (cnt > CAP) ? atomicAdd(spill_cursor, cnt - CAP) : 0;
    if (t < NPBK) cnt_[t] = 0;
    __syncthreads();
    for (int i = t; i < cnt; i += 512) {
        int pk = packed[cbeg + i];
        uint2 p8 = pay8[cbeg + i];
        atomicAdd(&cnt_[(pk >> 24) & (NPBK - 1)], 1);
        if (i < CAP) { spk[i] = pk; spay[i] = p8; }
        else {
            int sp = sbase_s + (i - CAP);
            if (sp < SPILL_E) { spill_pk[sp] = pk; spill_pay[sp] = p8; }
        }
    }
    __syncthreads();
    int v = (t < NPBK) ? cnt_[t] : 0;
    if (t < NPBK) sc[t] = v;
    __syncthreads();
    for (int off = 1; off < NPBK; off <<= 1) {
        int w = (t < NPBK && t >= off) ? sc[t - off] : 0;
        __syncthreads();
        if (t < NPBK) sc[t] += w;
        __syncthreads();
    }
    if (t < NPBK) {
        int ex = sc[t] - v;
        int node = (b << LOG_NPBK) + t;
        if (node <= N) offsets[node] = cbeg + ex;
        cnt_[t] = ex;
    }
    __syncthreads();
    for (int i = t; i < cnt; i += 512) {
        int pk; uint2 p8;
        bool ok = true;
        if (i < CAP) { pk = spk[i]; p8 = spay[i]; }
        else {
            int sp = sbase_s + (i - CAP);
            ok = (sp < SPILL_E);
            if (ok) { pk = spill_pk[sp]; p8 = spill_pay[sp]; }
        }
        if (ok) {
            int pos = cbeg + atomicAdd(&cnt_[(pk >> 24) & (NPBK - 1)], 1);
            packed[pos] = pk;
            pay8[pos] = p8;
        }
    }
}

// --- Fallback tiers 3/4 ---
constexpr int SCAN_BLOCK = 256;
constexpr int SCAN_ITEMS = 8;
constexpr int SCAN_CHUNK = SCAN_BLOCK * SCAN_ITEMS;

__global__ void __launch_bounds__(256) hist_kernel(
        const int* __restrict__ dst, int* __restrict__ counts, int E) {
    int e = blockIdx.x * blockDim.x + threadIdx.x;
    if (e < E) atomicAdd(&counts[dst[e]], 1);
}
__global__ void __launch_bounds__(SCAN_BLOCK) block_sum_kernel(
        const int* __restrict__ counts, int* __restrict__ bsums, int N) {
    __shared__ int sdata[SCAN_BLOCK];
    int base = blockIdx.x * SCAN_CHUNK;
    int sum = 0;
    for (int j = 0; j < SCAN_ITEMS; ++j) {
        int idx = base + j * SCAN_BLOCK + threadIdx.x;
        if (idx < N) sum += counts[idx];
    }
    sdata[threadIdx.x] = sum;
    __syncthreads();
    for (int off = SCAN_BLOCK / 2; off > 0; off >>= 1) {
        if (threadIdx.x < off) sdata[threadIdx.x] += sdata[threadIdx.x + off];
        __syncthreads();
    }
    if (threadIdx.x == 0) bsums[blockIdx.x] = sdata[0];
}
__global__ void scan_bsums_kernel(int* __restrict__ bsums, int nb) {
    if (threadIdx.x == 0 && blockIdx.x == 0) {
        int acc = 0;
        for (int i = 0; i < nb; ++i) { int v = bsums[i]; bsums[i] = acc; acc += v; }
    }
}
__global__ void __launch_bounds__(SCAN_BLOCK) scan_final_kernel(
        const int* __restrict__ counts, const int* __restrict__ bsums,
        int* __restrict__ offsets, int* __restrict__ cursors, int N, int E) {
    __shared__ int sdata[SCAN_BLOCK];
    int base = blockIdx.x * SCAN_CHUNK + threadIdx.x * SCAN_ITEMS;
    int local[SCAN_ITEMS];
    int tsum = 0;
    for (int j = 0; j < SCAN_ITEMS; ++j) {
        int idx = base + j;
        int v = (idx < N) ? counts[idx] : 0;
        local[j] = tsum;
        tsum += v;
    }
    sdata[threadIdx.x] = tsum;
    __syncthreads();
    for (int off = 1; off < SCAN_BLOCK; off <<= 1) {
        int v = (threadIdx.x >= off) ? sdata[threadIdx.x - off] : 0;
        __syncthreads();
        sdata[threadIdx.x] += v;
        __syncthreads();
    }
    int excl = sdata[threadIdx.x] - tsum + bsums[blockIdx.x];
    for (int j = 0; j < SCAN_ITEMS; ++j) {
        int idx = base + j;
        if (idx < N) { int o = excl + local[j]; offsets[idx] = o; cursors[idx] = o; }
    }
    if (blockIdx.x == 0 && threadIdx.x == 0) offsets[N] = E;
}
__global__ void __launch_bounds__(256) scatter_ids_kernel(
        const int* __restrict__ dst, int* __restrict__ cursors,
        int* __restrict__ eids, int E) {
    int e = blockIdx.x * blockDim.x + threadIdx.x;
    if (e < E) { int pos = atomicAdd(&cursors[dst[e]], 1); eids[pos] = e; }
}
__global__ void __launch_bounds__(US) accum_ids_kernel(
        const float* __restrict__ x, const float* __restrict__ sh,
        const int* __restrict__ src, const int* __restrict__ offsets,
        const int* __restrict__ eids, float* __restrict__ out) {
    int n = blockIdx.x;
    int t = threadIdx.x;
    int u = t >> 2, s = t & 3;
    int beg = offsets[n], end = offsets[n + 1];
    float acc = 0.f;
    for (int i = beg; i < end; ++i) {
        int e = eids[i];
        acc += x[src[e] * U_DIM + u] * sh[e * 4 + s];
    }
    out[(size_t)n * US + t] = acc;
}
__global__ void __launch_bounds__(US) atomic_kernel(
        const float* __restrict__ x, const float* __restrict__ sh,
        const int* __restrict__ src, const int* __restrict__ dst,
        float* __restrict__ out, int E) {
    int e = blockIdx.x;
    int t = threadIdx.x;
    float v = x[src[e] * U_DIM + (t >> 2)] * sh[e * 4 + (t & 3)];
    atomicAdd(&out[(size_t)dst[e] * US + t], v);
}

extern "C" void kernel_launch(void* const* d_in, const int* in_sizes, int n_in,
                              void* d_out, int out_size, void* d_ws, size_t ws_size,
                              hipStream_t stream) {
    const float* x  = (const float*)d_in[0];
    const float* sh = (const float*)d_in[1];
    const int* src  = (const int*)d_in[2];
    const int* dst  = (const int*)d_in[3];
    float* out = (float*)d_out;

    const int E = in_sizes[2];
    const int N = in_sizes[0] / U_DIM;
    const int xn4 = in_sizes[0] / 4;
    const int egrid = (E + 255) / 256;
    const int nb = (N + SCAN_CHUNK - 1) / SCAN_CHUNK;

    const int K1 = (N + C1_NPB - 1) >> C1_LOG;
    const int KF = (N + FINE_NPB - 1) >> FINE_LOG;
    const int EPB1 = (E + C1_NBLK - 1) / C1_NBLK;
    size_t need_main = (size_t)E * 24 + (size_t)in_sizes[0] * 2 +
                       (size_t)(N + 1 + 2 * KF + 2 + K1 + 1 +
                                2 * K1 * C1_NBLK) * 4;

    const int K = (N + NPBK - 1) >> LOG_NPBK;
    const int EPB = (E + NBLK - 1) / NBLK;
    size_t need_r7 = (size_t)E * 12 + (size_t)SPILL_E * 12 + (size_t)(N + 1) * 4 +
                     (size_t)(2 * K + 2) * 4 + (size_t)(2 * K * NBLK) * 4 +
                     (size_t)in_sizes[0] * 2;
    size_t need_ids = (size_t)E * 4 + (size_t)(3 * N + 1 + nb) * 4;

    if (K1 <= C1_MAXK && KF <= KF_MAX && N <= (1 << 21) &&
        (in_sizes[0] % 4 == 0) && ws_size >= need_main) {
        uint2* pay8A   = (uint2*)d_ws;
        uint2* pay8B   = pay8A + E;
        int* packedA   = (int*)(pay8B + E);
        int* packedB   = packedA + E;
        unsigned short* xb = (unsigned short*)(packedB + E);
        int* offsets   = (int*)(xb + in_sizes[0]);
        int* ccount_f  = offsets + N + 1;
        int* fbase     = ccount_f + KF;
        int* cbase     = fbase + KF + 1;
        int* cnt       = cbase + K1 + 1;
        int* base_tab  = cnt + K1 * C1_NBLK;

        hipMemsetAsync(ccount_f, 0, sizeof(int) * (size_t)KF, stream);
        xcvt_kernel<<<(xn4 + 255) / 256, 256, 0, stream>>>(
            (const float4*)x, (ushort4*)xb, xn4);
        c1_hist_kernel<<<C1_NBLK, 1024, 0, stream>>>(dst, ccount_f, cnt,
                                                     E, KF, K1, EPB1);
        c1_scan_kernel<<<1, 1024, 0, stream>>>(ccount_f, fbase, cbase, offsets,
                                               KF, K1, N, E);
        c1_cbase_kernel<<<K1, C1_NBLK, 0, stream>>>(cnt, cbase, base_tab);
        c1_scatter_kernel<<<C1_NBLK, 1024, 0, stream>>>(dst, src, (const float4*)sh,
                                                        base_tab, pay8A, packedA,
                                                        E, K1, EPB1);
        c2_sort_kernel<<<KF, 1024, 0, stream>>>(cbase, fbase, offsets,
                                                pay8A, packedA, pay8B, packedB, N);
        accum_kernel<<<(N + 31) / 32, 256, 0, stream>>>(xb, pay8B, packedB,
                                                        offsets, out, 0x1FFFFF, N);
    } else if (K <= MAXK && (in_sizes[0] % 4 == 0) && ws_size >= need_r7) {
        uint2* pay8      = (uint2*)d_ws;
        uint2* spill_pay = pay8 + E;
        int* packed      = (int*)(spill_pay + SPILL_E);
        int* spill_pk    = packed + E;
        int* offsets     = spill_pk + SPILL_E;
        int* ccount      = offsets + N + 1;
        int* cbase       = ccount + K;
        int* cnt         = cbase + K + 1;
        int* base_tab    = cnt + K * NBLK;
        int* spill_cur   = base_tab + K * NBLK;
        unsigned short* xb = (unsigned short*)(spill_cur + 1);

        hipMemsetAsync(ccount, 0, sizeof(int) * (size_t)K, stream);
        xcvt_kernel<<<(xn4 + 255) / 256, 256, 0, stream>>>(
            (const float4*)x, (ushort4*)xb, xn4);
        coarse_hist_kernel<<<NBLK, 1024, 0, stream>>>(dst, ccount, cnt, E, K, EPB);
        coarse_scan_kernel<<<1, 1024, 0, stream>>>(ccount, cbase, offsets,
                                                   spill_cur, K, N, E);
        chunk_base_kernel<<<K, NBLK, 0, stream>>>(cnt, cbase, base_tab);
        coarse_scatter_kernel<<<NBLK, 1024, 0, stream>>>(dst, src, (const float4*)sh,
                                                         base_tab, pay8, packed,
                                                         E, K, EPB);
        fine_sort_kernel<<<K, 512, 0, stream>>>(cbase, offsets, pay8, packed,
                                                spill_pay, spill_pk, spill_cur, N);
        accum_kernel<<<(N + 31) / 32, 256, 0, stream>>>(xb, pay8, packed,
                                                        offsets, out, 0xFFFFFF, N);
    } else if (ws_size >= need_ids) {
        int* eids    = (int*)d_ws;
        int* counts  = eids + E;
        int* offsets = counts + N;
        int* cursors = offsets + N + 1;
        int* bsums   = cursors + N;

        hipMemsetAsync(counts, 0, sizeof(int) * (size_t)N, stream);
        hist_kernel<<<egrid, 256, 0, stream>>>(dst, counts, E);
        block_sum_kernel<<<nb, SCAN_BLOCK, 0, stream>>>(counts, bsums, N);
        scan_bsums_kernel<<<1, 64, 0, stream>>>(bsums, nb);
        scan_final_kernel<<<nb, SCAN_BLOCK, 0, stream>>>(counts, bsums, offsets, cursors, N, E);
        scatter_ids_kernel<<<egrid, 256, 0, stream>>>(dst, cursors, eids, E);
        accum_ids_kernel<<<N, US, 0, stream>>>(x, sh, src, offsets, eids, out);
    } else {
        hipMemsetAsync(out, 0, sizeof(float) * (size_t)out_size, stream);
        atomic_kernel<<<E, US, 0, stream>>>(x, sh, src, dst, out, E);
    }
}

// Round 21
// 182.024 us; speedup vs baseline: 1.0826x; 1.0247x over previous
//
#include <hip/hip_runtime.h>

// out[n, u*4+s] = sum_{e: dst[e]==n} x[src[e], u] * sh[e, s]
// N=100000, U=32, S=4, E=3200000.
//
// Ledger of lessons:
//  R2: bulk LDS float atomics / single-counter atomics = serial floor.
//  R4/R5/R7: scattered writes, many streams/block = HBM write amp.
//  R8: few deep-serial blocks lose to many shallow blocks.
//  R9/R13: xb/sh are L3-resident; FETCH is L2-fill traffic.
//  R10: NT loads on shared streams re-fetch lines.
//  R11/R15/R16: accum: contiguous ranges, 4 nodes/wave, 16 lanes/edge,
//      zero reduction: 99->87->61.6us (PROVEN BEST).
//  R12: lane-widening WITH cross-lane reduction = loss.
//  R13: XCD-swizzle on undefined block->XCD mapping: reverted.
//  R17: c1 subchunk LDS-sort + burst write kills write amp.
//  R18/R19: c2 single-read + 1024 threads (32 waves/CU): off top-5.
//  R20: 8 nodes/wave raised FETCH 147->170MB (stream-concurrency L2 thrash);
//      4 nodes/wave is the sweet spot. REVERTED.
// R21: accum restored to R19's proven 4-nodes/wave form. No other changes.

#define U_DIM 32
#define US 128

__device__ inline unsigned f2bf(float f) {          // RNE float->bf16 bits
    unsigned u = __float_as_uint(f);
    return (u + 0x7FFF + ((u >> 16) & 1)) >> 16;
}
__device__ inline float bfl(unsigned w) { return __uint_as_float(w << 16); }
__device__ inline float bfh(unsigned w) { return __uint_as_float(w & 0xFFFF0000u); }

__global__ void __launch_bounds__(256) xcvt_kernel(
        const float4* __restrict__ x4, ushort4* __restrict__ xb4, int n4) {
    int i = blockIdx.x * 256 + threadIdx.x;
    if (i < n4) {
        float4 v = x4[i];
        ushort4 r;
        r.x = (unsigned short)f2bf(v.x);
        r.y = (unsigned short)f2bf(v.y);
        r.z = (unsigned short)f2bf(v.z);
        r.w = (unsigned short)f2bf(v.w);
        xb4[i] = r;
    }
}

// =================== PRIMARY PATH ===================
#define C1_LOG 9
#define C1_NPB 512
#define C1_MAXK 256
#define C1_NBLK 256
#define FINE_LOG 7
#define FINE_NPB 128
#define KF_MAX 1024
#define SCAP 5120             // LDS-staged edges per fine bucket (mean 4082)
#define SCH 4096              // c1_scatter subchunk (LDS-sorted burst unit)

// Fine-granularity (128-node) histogram; also per-chunk coarse counts.
__global__ void __launch_bounds__(1024) c1_hist_kernel(
        const int* __restrict__ dst, int* __restrict__ ccount_f,
        int* __restrict__ cnt, int E, int KF, int K1, int EPB) {
    __shared__ int h[KF_MAX];
    for (int b = threadIdx.x; b < KF; b += 1024) h[b] = 0;
    __syncthreads();
    int base = blockIdx.x * EPB;
    int lim = min(EPB, E - base);
    for (int i = threadIdx.x; i < lim; i += 1024)
        atomicAdd(&h[dst[base + i] >> FINE_LOG], 1);
    __syncthreads();
    for (int b = threadIdx.x; b < KF; b += 1024) {
        int c = h[b];
        if (c) atomicAdd(&ccount_f[b], c);
    }
    for (int b = threadIdx.x; b < K1; b += 1024) {
        int c = 0;
        #pragma unroll
        for (int k = 0; k < 4; ++k) {
            int f = 4 * b + k;
            if (f < KF) c += h[f];
        }
        cnt[b * C1_NBLK + blockIdx.x] = c;
    }
}

// One scan over KF fine counts -> fbase; cbase derived; offsets[N]=E.
__global__ void __launch_bounds__(1024) c1_scan_kernel(
        const int* __restrict__ ccount_f, int* __restrict__ fbase,
        int* __restrict__ cbase, int* __restrict__ offsets,
        int KF, int K1, int N, int E) {
    __shared__ int sc[1024];
    int t = threadIdx.x;
    int v = (t < KF) ? ccount_f[t] : 0;
    sc[t] = v;
    __syncthreads();
    for (int off = 1; off < 1024; off <<= 1) {
        int w = (t >= off) ? sc[t - off] : 0;
        __syncthreads();
        sc[t] += w;
        __syncthreads();
    }
    if (t < KF) fbase[t] = sc[t] - v;
    __syncthreads();
    if (t < K1) {
        int f = 4 * t;
        cbase[t] = (f < KF) ? (sc[f] - ccount_f[f]) : E;
    }
    if (t == 0) { fbase[KF] = E; cbase[K1] = E; offsets[N] = E; }
}

__global__ void __launch_bounds__(C1_NBLK) c1_cbase_kernel(
        const int* __restrict__ cnt, const int* __restrict__ cbase,
        int* __restrict__ base_tab) {
    __shared__ int sc[C1_NBLK];
    int b = blockIdx.x;
    int t = threadIdx.x;
    int v = cnt[b * C1_NBLK + t];
    sc[t] = v;
    __syncthreads();
    for (int off = 1; off < C1_NBLK; off <<= 1) {
        int w = (t >= off) ? sc[t - off] : 0;
        __syncthreads();
        sc[t] += w;
        __syncthreads();
    }
    base_tab[b * C1_NBLK + t] = cbase[b] + sc[t] - v;
}

// R17: subchunk LDS counting-sort + burst write. Writes for each output line
// arrive back-to-back from consecutive lanes -> L2 write-combining succeeds.
__global__ void __launch_bounds__(1024) c1_scatter_kernel(
        const int* __restrict__ dst, const int* __restrict__ src,
        const float4* __restrict__ sh, const int* __restrict__ base_tab,
        uint2* __restrict__ pay8A, int* __restrict__ packedA,
        int E, int K1, int EPB) {
    __shared__ uint2 spay[SCH];           // 32 KB
    __shared__ int   spk[SCH];            // 16 KB
    __shared__ unsigned char sbkt[SCH];   // 4 KB
    __shared__ int   hist[C1_MAXK];
    __shared__ int   lo[C1_MAXK];
    __shared__ int   scur[C1_MAXK];
    __shared__ int   gcur[C1_MAXK];
    __shared__ int   sc[C1_MAXK];
    int t = threadIdx.x;
    for (int b = t; b < K1; b += 1024)
        gcur[b] = base_tab[b * C1_NBLK + blockIdx.x];
    int base = blockIdx.x * EPB;
    int lim = min(EPB, E - base);

    for (int sb = 0; sb < lim; sb += SCH) {
        int sublen = min(SCH, lim - sb);
        for (int b = t; b < K1; b += 1024) hist[b] = 0;
        __syncthreads();
        int bk[4], pk[4];
        uint2 pv[4];
        bool vld[4];
        #pragma unroll
        for (int k = 0; k < 4; ++k) {
            int idx = t + k * 1024;
            vld[k] = (idx < sublen);
            if (vld[k]) {
                int e = base + sb + idx;
                int d = dst[e];
                bk[k] = d >> C1_LOG;
                float4 s4 = sh[e];
                pv[k] = make_uint2(f2bf(s4.x) | (f2bf(s4.y) << 16),
                                   f2bf(s4.z) | (f2bf(s4.w) << 16));
                pk[k] = ((d & (C1_NPB - 1)) << 21) | src[e];
                atomicAdd(&hist[bk[k]], 1);
            }
        }
        __syncthreads();
        if (t < C1_MAXK) sc[t] = (t < K1) ? hist[t] : 0;
        __syncthreads();
        for (int off = 1; off < C1_MAXK; off <<= 1) {
            int w = 0;
            if (t < C1_MAXK && t >= off) w = sc[t - off];
            __syncthreads();
            if (t < C1_MAXK) sc[t] += w;
            __syncthreads();
        }
        if (t < C1_MAXK) {
            int excl = sc[t] - ((t < K1) ? hist[t] : 0);
            lo[t] = excl;
            scur[t] = excl;
        }
        __syncthreads();
        #pragma unroll
        for (int k = 0; k < 4; ++k) {
            if (vld[k]) {
                int pos = atomicAdd(&scur[bk[k]], 1);
                spk[pos] = pk[k];
                spay[pos] = pv[k];
                sbkt[pos] = (unsigned char)bk[k];
            }
        }
        __syncthreads();
        for (int i = t; i < sublen; i += 1024) {
            int b = sbkt[i];
            int gd = gcur[b] + (i - lo[b]);
            packedA[gd] = spk[i];
            pay8A[gd] = spay[i];
        }
        __syncthreads();
        if (t < K1) gcur[t] += hist[t];
        __syncthreads();
    }
}

// R19: one block per fine bucket, 1024 threads (2 blk/CU x 1024 = 32 waves/CU).
// Single read of parent range; matching edges staged UNSORTED in LDS (wave-
// aggregated ballot reservation), then placed LDS->global sorted.
__global__ void __launch_bounds__(1024) c2_sort_kernel(
        const int* __restrict__ cbase, const int* __restrict__ fbase,
        int* __restrict__ offsets, const uint2* __restrict__ pay8A,
        const int* __restrict__ packedA, uint2* __restrict__ pay8B,
        int* __restrict__ packedB, int N) {
    __shared__ uint2 spay[SCAP];          // 40 KB
    __shared__ int   spk[SCAP];           // 20 KB
    __shared__ int   hh[FINE_NPB];
    __shared__ int   scur[FINE_NPB];
    __shared__ int   stot;
    int fb = blockIdx.x;
    int t = threadIdx.x;
    int lane = t & 63;
    int parent = fb >> 2, sub = fb & 3;
    int cbeg = cbase[parent], cend = cbase[parent + 1];
    int fbeg = fbase[fb];
    int cnt = fbase[fb + 1] - fbeg;
    if (t < FINE_NPB) hh[t] = 0;
    if (t == 0) stot = 0;
    __syncthreads();

    if (cnt <= SCAP) {
        for (int i = cbeg + t; i < cend; i += 1024) {
            int pk = packedA[i];
            int nc = (pk >> 21) & (C1_NPB - 1);
            bool m = ((nc >> FINE_LOG) == sub);
            unsigned long long mask = __ballot(m);
            if (m) {
                atomicAdd(&hh[nc & (FINE_NPB - 1)], 1);
                int leader = __ffsll((long long)mask) - 1;
                int base_ = 0;
                if (lane == leader) base_ = atomicAdd(&stot, __popcll(mask));
                base_ = __shfl(base_, leader);
                int pos = base_ + __popcll(mask & ((1ull << lane) - 1ull));
                spk[pos] = pk;
                spay[pos] = pay8A[i];
            }
        }
        __syncthreads();
        int v = (t < FINE_NPB) ? hh[t] : 0;
        if (t < FINE_NPB) hh[t] = v;
        __syncthreads();
        for (int off = 1; off < FINE_NPB; off <<= 1) {
            int w = (t < FINE_NPB && t >= off) ? hh[t - off] : 0;
            __syncthreads();
            if (t < FINE_NPB) hh[t] += w;
            __syncthreads();
        }
        if (t < FINE_NPB) {
            int excl = hh[t] - v;
            scur[t] = fbeg + excl;
            int node = (fb << FINE_LOG) + t;
            if (node < N) offsets[node] = fbeg + excl;
        }
        __syncthreads();
        for (int j = t; j < cnt; j += 1024) {
            int pk = spk[j];
            int node = (pk >> 21) & (FINE_NPB - 1);
            int pos = atomicAdd(&scur[node], 1);
            packedB[pos] = pk;
            pay8B[pos] = spay[j];
        }
    } else {
        for (int i = cbeg + t; i < cend; i += 1024) {
            int nc = (packedA[i] >> 21) & (C1_NPB - 1);
            if ((nc >> FINE_LOG) == sub)
                atomicAdd(&hh[nc & (FINE_NPB - 1)], 1);
        }
        __syncthreads();
        int v = (t < FINE_NPB) ? hh[t] : 0;
        if (t < FINE_NPB) hh[t] = v;
        __syncthreads();
        for (int off = 1; off < FINE_NPB; off <<= 1) {
            int w = (t < FINE_NPB && t >= off) ? hh[t - off] : 0;
            __syncthreads();
            if (t < FINE_NPB) hh[t] += w;
            __syncthreads();
        }
        if (t < FINE_NPB) {
            int excl = hh[t] - v;
            scur[t] = fbeg + excl;
            int node = (fb << FINE_LOG) + t;
            if (node < N) offsets[node] = fbeg + excl;
        }
        __syncthreads();
        for (int i = cbeg + t; i < cend; i += 1024) {
            int pk = packedA[i];
            int nc = (pk >> 21) & (C1_NPB - 1);
            if ((nc >> FINE_LOG) == sub) {
                int pos = atomicAdd(&scur[nc & (FINE_NPB - 1)], 1);
                packedB[pos] = pk;
                pay8B[pos] = pay8A[i];
            }
        }
    }
}

// R21 accum (= R19 proven): 256-thr block = 4 waves; each wave handles 4 nodes
// (grp=lane>>4). Lane l=lane&15 covers u={2l,2l+1} via one ushort2 x-load.
// Per edge: 16-lane group broadcast-loads payload, 8 FMAs into a[8].
// NO reduction, NO LDS; each lane stores 8 contiguous floats. Unroll-4 MLP.
__global__ void __launch_bounds__(256) accum_kernel(
        const unsigned short* __restrict__ xb, const uint2* __restrict__ pay8,
        const int* __restrict__ packed, const int* __restrict__ offsets,
        float* __restrict__ out, int smask, int N) {
    int wave = threadIdx.x >> 6;
    int lane = threadIdx.x & 63;
    int grp = lane >> 4;              // node within wave
    int l = lane & 15;                // covers u = 2l, 2l+1
    int n = blockIdx.x * 16 + wave * 4 + grp;
    if (n >= N) return;
    int beg = offsets[n], end = offsets[n + 1];
    int u2 = l << 1;
    float a0 = 0.f, a1 = 0.f, a2 = 0.f, a3 = 0.f;
    float a4 = 0.f, a5 = 0.f, a6 = 0.f, a7 = 0.f;
    int i = beg;
    for (; i + 3 < end; i += 4) {
        int pk0 = packed[i], pk1 = packed[i + 1];
        int pk2 = packed[i + 2], pk3 = packed[i + 3];
        uint2 q0 = pay8[i], q1 = pay8[i + 1];
        uint2 q2 = pay8[i + 2], q3 = pay8[i + 3];
        ushort2 xv0 = *reinterpret_cast<const ushort2*>(
            &xb[(size_t)(pk0 & smask) * U_DIM + u2]);
        ushort2 xv1 = *reinterpret_cast<const ushort2*>(
            &xb[(size_t)(pk1 & smask) * U_DIM + u2]);
        ushort2 xv2 = *reinterpret_cast<const ushort2*>(
            &xb[(size_t)(pk2 & smask) * U_DIM + u2]);
        ushort2 xv3 = *reinterpret_cast<const ushort2*>(
            &xb[(size_t)(pk3 & smask) * U_DIM + u2]);
        {
            float xa = bfl((unsigned)xv0.x), xc = bfl((unsigned)xv0.y);
            float s0 = bfl(q0.x), s1 = bfh(q0.x), s2 = bfl(q0.y), s3 = bfh(q0.y);
            a0 += xa * s0; a1 += xa * s1; a2 += xa * s2; a3 += xa * s3;
            a4 += xc * s0; a5 += xc * s1; a6 += xc * s2; a7 += xc * s3;
        }
        {
            float xa = bfl((unsigned)xv1.x), xc = bfl((unsigned)xv1.y);
            float s0 = bfl(q1.x), s1 = bfh(q1.x), s2 = bfl(q1.y), s3 = bfh(q1.y);
            a0 += xa * s0; a1 += xa * s1; a2 += xa * s2; a3 += xa * s3;
            a4 += xc * s0; a5 += xc * s1; a6 += xc * s2; a7 += xc * s3;
        }
        {
            float xa = bfl((unsigned)xv2.x), xc = bfl((unsigned)xv2.y);
            float s0 = bfl(q2.x), s1 = bfh(q2.x), s2 = bfl(q2.y), s3 = bfh(q2.y);
            a0 += xa * s0; a1 += xa * s1; a2 += xa * s2; a3 += xa * s3;
            a4 += xc * s0; a5 += xc * s1; a6 += xc * s2; a7 += xc * s3;
        }
        {
            float xa = bfl((unsigned)xv3.x), xc = bfl((unsigned)xv3.y);
            float s0 = bfl(q3.x), s1 = bfh(q3.x), s2 = bfl(q3.y), s3 = bfh(q3.y);
            a0 += xa * s0; a1 += xa * s1; a2 += xa * s2; a3 += xa * s3;
            a4 += xc * s0; a5 += xc * s1; a6 += xc * s2; a7 += xc * s3;
        }
    }
    for (; i < end; ++i) {
        int pk = packed[i];
        uint2 q = pay8[i];
        ushort2 xv = *reinterpret_cast<const ushort2*>(
            &xb[(size_t)(pk & smask) * U_DIM + u2]);
        float xa = bfl((unsigned)xv.x), xc = bfl((unsigned)xv.y);
        float s0 = bfl(q.x), s1 = bfh(q.x), s2 = bfl(q.y), s3 = bfh(q.y);
        a0 += xa * s0; a1 += xa * s1; a2 += xa * s2; a3 += xa * s3;
        a4 += xc * s0; a5 += xc * s1; a6 += xc * s2; a7 += xc * s3;
    }
    size_t obase = (size_t)n * US + (size_t)u2 * 4;
    *reinterpret_cast<float4*>(&out[obase])     = make_float4(a0, a1, a2, a3);
    *reinterpret_cast<float4*>(&out[obase + 4]) = make_float4(a4, a5, a6, a7);
}

// =================== TIER-2: proven R7 path ===================
#define LOG_NPBK 7
#define NPBK 128
#define MAXK 1024
#define NBLK 256
#define CAP 5120
#define SPILL_E 1000000

__global__ void __launch_bounds__(1024) coarse_hist_kernel(
        const int* __restrict__ dst, int* __restrict__ ccount,
        int* __restrict__ cnt, int E, int K, int EPB) {
    __shared__ int h[MAXK];
    for (int b = threadIdx.x; b < K; b += 1024) h[b] = 0;
    __syncthreads();
    int base = blockIdx.x * EPB;
    int lim = min(EPB, E - base);
    for (int i = threadIdx.x; i < lim; i += 1024)
        atomicAdd(&h[dst[base + i] >> LOG_NPBK], 1);
    __syncthreads();
    for (int b = threadIdx.x; b < K; b += 1024) {
        int c = h[b];
        cnt[b * NBLK + blockIdx.x] = c;
        if (c) atomicAdd(&ccount[b], c);
    }
}

__global__ void __launch_bounds__(1024) coarse_scan_kernel(
        const int* __restrict__ ccount, int* __restrict__ cbase,
        int* __restrict__ offsets, int* __restrict__ spill_cursor,
        int K, int N, int E) {
    __shared__ int sc[1024];
    int t = threadIdx.x;
    int v = (t < K) ? ccount[t] : 0;
    sc[t] = v;
    __syncthreads();
    for (int off = 1; off < 1024; off <<= 1) {
        int w = (t >= off) ? sc[t - off] : 0;
        __syncthreads();
        sc[t] += w;
        __syncthreads();
    }
    if (t < K) cbase[t] = sc[t] - v;
    if (t == 0) { cbase[K] = E; offsets[N] = E; *spill_cursor = 0; }
}

__global__ void __launch_bounds__(NBLK) chunk_base_kernel(
        const int* __restrict__ cnt, const int* __restrict__ cbase,
        int* __restrict__ base_tab) {
    __shared__ int sc[NBLK];
    int b = blockIdx.x;
    int t = threadIdx.x;
    int v = cnt[b * NBLK + t];
    sc[t] = v;
    __syncthreads();
    for (int off = 1; off < NBLK; off <<= 1) {
        int w = (t >= off) ? sc[t - off] : 0;
        __syncthreads();
        sc[t] += w;
        __syncthreads();
    }
    base_tab[b * NBLK + t] = cbase[b] + sc[t] - v;
}

__global__ void __launch_bounds__(1024) coarse_scatter_kernel(
        const int* __restrict__ dst, const int* __restrict__ src,
        const float4* __restrict__ sh, const int* __restrict__ base_tab,
        uint2* __restrict__ pay8, int* __restrict__ packed,
        int E, int K, int EPB) {
    __shared__ int cur[MAXK];
    for (int b = threadIdx.x; b < K; b += 1024)
        cur[b] = base_tab[b * NBLK + blockIdx.x];
    __syncthreads();
    int base = blockIdx.x * EPB;
    int lim = min(EPB, E - base);
    for (int i = threadIdx.x; i < lim; i += 1024) {
        int e = base + i;
        int d = dst[e];
        int b = d >> LOG_NPBK;
        int pos = atomicAdd(&cur[b], 1);
        float4 s4 = sh[e];
        pay8[pos] = make_uint2(f2bf(s4.x) | (f2bf(s4.y) << 16),
                               f2bf(s4.z) | (f2bf(s4.w) << 16));
        packed[pos] = ((d & (NPBK - 1)) << 24) | src[e];
    }
}

__global__ void __launch_bounds__(512) fine_sort_kernel(
        const int* __restrict__ cbase, int* __restrict__ offsets,
        uint2* __restrict__ pay8, int* __restrict__ packed,
        uint2* __restrict__ spill_pay, int* __restrict__ spill_pk,
        int* __restrict__ spill_cursor, int N) {
    __shared__ uint2 spay[CAP];
    __shared__ int   spk[CAP];
    __shared__ int   cnt_[NPBK];
    __shared__ int   sc[NPBK];
    __shared__ int   sbase_s;
    int b = blockIdx.x;
    int t = threadIdx.x;
    int cbeg = cbase[b], cend = cbase[b + 1];
    int cnt = cend - cbeg;
    if (t == 0) sbase_s = (cnt > CAP) ? atomicAdd(spill_cursor, cnt - CAP) : 0;
    if (t < NPBK) cnt_[t] = 0;
    __syncthreads();
    for (int i = t; i < cnt; i += 512) {
        int pk = packed[cbeg + i];
        uint2 p8 = pay8[cbeg + i];
        atomicAdd(&cnt_[(pk >> 24) & (NPBK - 1)], 1);
        if (i < CAP) { spk[i] = pk; spay[i] = p8; }
        else {
            int sp = sbase_s + (i - CAP);
            if (sp < SPILL_E) { spill_pk[sp] = pk; spill_pay[sp] = p8; }
        }
    }
    __syncthreads();
    int v = (t < NPBK) ? cnt_[t] : 0;
    if (t < NPBK) sc[t] = v;
    __syncthreads();
    for (int off = 1; off < NPBK; off <<= 1) {
        int w = (t < NPBK && t >= off) ? sc[t - off] : 0;
        __syncthreads();
        if (t < NPBK) sc[t] += w;
        __syncthreads();
    }
    if (t < NPBK) {
        int ex = sc[t] - v;
        int node = (b << LOG_NPBK) + t;
        if (node <= N) offsets[node] = cbeg + ex;
        cnt_[t] = ex;
    }
    __syncthreads();
    for (int i = t; i < cnt; i += 512) {
        int pk; uint2 p8;
        bool ok = true;
        if (i < CAP) { pk = spk[i]; p8 = spay[i]; }
        else {
            int sp = sbase_s + (i - CAP);
            ok = (sp < SPILL_E);
            if (ok) { pk = spill_pk[sp]; p8 = spill_pay[sp]; }
        }
        if (ok) {
            int pos = cbeg + atomicAdd(&cnt_[(pk >> 24) & (NPBK - 1)], 1);
            packed[pos] = pk;
            pay8[pos] = p8;
        }
    }
}

// --- Fallback tiers 3/4 ---
constexpr int SCAN_BLOCK = 256;
constexpr int SCAN_ITEMS = 8;
constexpr int SCAN_CHUNK = SCAN_BLOCK * SCAN_ITEMS;

__global__ void __launch_bounds__(256) hist_kernel(
        const int* __restrict__ dst, int* __restrict__ counts, int E) {
    int e = blockIdx.x * blockDim.x + threadIdx.x;
    if (e < E) atomicAdd(&counts[dst[e]], 1);
}
__global__ void __launch_bounds__(SCAN_BLOCK) block_sum_kernel(
        const int* __restrict__ counts, int* __restrict__ bsums, int N) {
    __shared__ int sdata[SCAN_BLOCK];
    int base = blockIdx.x * SCAN_CHUNK;
    int sum = 0;
    for (int j = 0; j < SCAN_ITEMS; ++j) {
        int idx = base + j * SCAN_BLOCK + threadIdx.x;
        if (idx < N) sum += counts[idx];
    }
    sdata[threadIdx.x] = sum;
    __syncthreads();
    for (int off = SCAN_BLOCK / 2; off > 0; off >>= 1) {
        if (threadIdx.x < off) sdata[threadIdx.x] += sdata[threadIdx.x + off];
        __syncthreads();
    }
    if (threadIdx.x == 0) bsums[blockIdx.x] = sdata[0];
}
__global__ void scan_bsums_kernel(int* __restrict__ bsums, int nb) {
    if (threadIdx.x == 0 && blockIdx.x == 0) {
        int acc = 0;
        for (int i = 0; i < nb; ++i) { int v = bsums[i]; bsums[i] = acc; acc += v; }
    }
}
__global__ void __launch_bounds__(SCAN_BLOCK) scan_final_kernel(
        const int* __restrict__ counts, const int* __restrict__ bsums,
        int* __restrict__ offsets, int* __restrict__ cursors, int N, int E) {
    __shared__ int sdata[SCAN_BLOCK];
    int base = blockIdx.x * SCAN_CHUNK + threadIdx.x * SCAN_ITEMS;
    int local[SCAN_ITEMS];
    int tsum = 0;
    for (int j = 0; j < SCAN_ITEMS; ++j) {
        int idx = base + j;
        int v = (idx < N) ? counts[idx] : 0;
        local[j] = tsum;
        tsum += v;
    }
    sdata[threadIdx.x] = tsum;
    __syncthreads();
    for (int off = 1; off < SCAN_BLOCK; off <<= 1) {
        int v = (threadIdx.x >= off) ? sdata[threadIdx.x - off] : 0;
        __syncthreads();
        sdata[threadIdx.x] += v;
        __syncthreads();
    }
    int excl = sdata[threadIdx.x] - tsum + bsums[blockIdx.x];
    for (int j = 0; j < SCAN_ITEMS; ++j) {
        int idx = base + j;
        if (idx < N) { int o = excl + local[j]; offsets[idx] = o; cursors[idx] = o; }
    }
    if (blockIdx.x == 0 && threadIdx.x == 0) offsets[N] = E;
}
__global__ void __launch_bounds__(256) scatter_ids_kernel(
        const int* __restrict__ dst, int* __restrict__ cursors,
        int* __restrict__ eids, int E) {
    int e = blockIdx.x * blockDim.x + threadIdx.x;
    if (e < E) { int pos = atomicAdd(&cursors[dst[e]], 1); eids[pos] = e; }
}
__global__ void __launch_bounds__(US) accum_ids_kernel(
        const float* __restrict__ x, const float* __restrict__ sh,
        const int* __restrict__ src, const int* __restrict__ offsets,
        const int* __restrict__ eids, float* __restrict__ out) {
    int n = blockIdx.x;
    int t = threadIdx.x;
    int u = t >> 2, s = t & 3;
    int beg = offsets[n], end = offsets[n + 1];
    float acc = 0.f;
    for (int i = beg; i < end; ++i) {
        int e = eids[i];
        acc += x[src[e] * U_DIM + u] * sh[e * 4 + s];
    }
    out[(size_t)n * US + t] = acc;
}
__global__ void __launch_bounds__(US) atomic_kernel(
        const float* __restrict__ x, const float* __restrict__ sh,
        const int* __restrict__ src, const int* __restrict__ dst,
        float* __restrict__ out, int E) {
    int e = blockIdx.x;
    int t = threadIdx.x;
    float v = x[src[e] * U_DIM + (t >> 2)] * sh[e * 4 + (t & 3)];
    atomicAdd(&out[(size_t)dst[e] * US + t], v);
}

extern "C" void kernel_launch(void* const* d_in, const int* in_sizes, int n_in,
                              void* d_out, int out_size, void* d_ws, size_t ws_size,
                              hipStream_t stream) {
    const float* x  = (const float*)d_in[0];
    const float* sh = (const float*)d_in[1];
    const int* src  = (const int*)d_in[2];
    const int* dst  = (const int*)d_in[3];
    float* out = (float*)d_out;

    const int E = in_sizes[2];
    const int N = in_sizes[0] / U_DIM;
    const int xn4 = in_sizes[0] / 4;
    const int egrid = (E + 255) / 256;
    const int nb = (N + SCAN_CHUNK - 1) / SCAN_CHUNK;

    const int K1 = (N + C1_NPB - 1) >> C1_LOG;
    const int KF = (N + FINE_NPB - 1) >> FINE_LOG;
    const int EPB1 = (E + C1_NBLK - 1) / C1_NBLK;
    size_t need_main = (size_t)E * 24 + (size_t)in_sizes[0] * 2 +
                       (size_t)(N + 1 + 2 * KF + 2 + K1 + 1 +
                                2 * K1 * C1_NBLK) * 4;

    const int K = (N + NPBK - 1) >> LOG_NPBK;
    const int EPB = (E + NBLK - 1) / NBLK;
    size_t need_r7 = (size_t)E * 12 + (size_t)SPILL_E * 12 + (size_t)(N + 1) * 4 +
                     (size_t)(2 * K + 2) * 4 + (size_t)(2 * K * NBLK) * 4 +
                     (size_t)in_sizes[0] * 2;
    size_t need_ids = (size_t)E * 4 + (size_t)(3 * N + 1 + nb) * 4;

    if (K1 <= C1_MAXK && KF <= KF_MAX && N <= (1 << 21) &&
        (in_sizes[0] % 4 == 0) && ws_size >= need_main) {
        uint2* pay8A   = (uint2*)d_ws;
        uint2* pay8B   = pay8A + E;
        int* packedA   = (int*)(pay8B + E);
        int* packedB   = packedA + E;
        unsigned short* xb = (unsigned short*)(packedB + E);
        int* offsets   = (int*)(xb + in_sizes[0]);
        int* ccount_f  = offsets + N + 1;
        int* fbase     = ccount_f + KF;
        int* cbase     = fbase + KF + 1;
        int* cnt       = cbase + K1 + 1;
        int* base_tab  = cnt + K1 * C1_NBLK;

        hipMemsetAsync(ccount_f, 0, sizeof(int) * (size_t)KF, stream);
        xcvt_kernel<<<(xn4 + 255) / 256, 256, 0, stream>>>(
            (const float4*)x, (ushort4*)xb, xn4);
        c1_hist_kernel<<<C1_NBLK, 1024, 0, stream>>>(dst, ccount_f, cnt,
                                                     E, KF, K1, EPB1);
        c1_scan_kernel<<<1, 1024, 0, stream>>>(ccount_f, fbase, cbase, offsets,
                                               KF, K1, N, E);
        c1_cbase_kernel<<<K1, C1_NBLK, 0, stream>>>(cnt, cbase, base_tab);
        c1_scatter_kernel<<<C1_NBLK, 1024, 0, stream>>>(dst, src, (const float4*)sh,
                                                        base_tab, pay8A, packedA,
                                                        E, K1, EPB1);
        c2_sort_kernel<<<KF, 1024, 0, stream>>>(cbase, fbase, offsets,
                                                pay8A, packedA, pay8B, packedB, N);
        accum_kernel<<<(N + 15) / 16, 256, 0, stream>>>(xb, pay8B, packedB,
                                                        offsets, out, 0x1FFFFF, N);
    } else if (K <= MAXK && (in_sizes[0] % 4 == 0) && ws_size >= need_r7) {
        uint2* pay8      = (uint2*)d_ws;
        uint2* spill_pay = pay8 + E;
        int* packed      = (int*)(spill_pay + SPILL_E);
        int* spill_pk    = packed + E;
        int* offsets     = spill_pk + SPILL_E;
        int* ccount      = offsets + N + 1;
        int* cbase       = ccount + K;
        int* cnt         = cbase + K + 1;
        int* base_tab    = cnt + K * NBLK;
        int* spill_cur   = base_tab + K * NBLK;
        unsigned short* xb = (unsigned short*)(spill_cur + 1);

        hipMemsetAsync(ccount, 0, sizeof(int) * (size_t)K, stream);
        xcvt_kernel<<<(xn4 + 255) / 256, 256, 0, stream>>>(
            (const float4*)x, (ushort4*)xb, xn4);
        coarse_hist_kernel<<<NBLK, 1024, 0, stream>>>(dst, ccount, cnt, E, K, EPB);
        coarse_scan_kernel<<<1, 1024, 0, stream>>>(ccount, cbase, offsets,
                                                   spill_cur, K, N, E);
        chunk_base_kernel<<<K, NBLK, 0, stream>>>(cnt, cbase, base_tab);
        coarse_scatter_kernel<<<NBLK, 1024, 0, stream>>>(dst, src, (const float4*)sh,
                                                         base_tab, pay8, packed,
                                                         E, K, EPB);
        fine_sort_kernel<<<K, 512, 0, stream>>>(cbase, offsets, pay8, packed,
                                                spill_pay, spill_pk, spill_cur, N);
        accum_kernel<<<(N + 15) / 16, 256, 0, stream>>>(xb, pay8, packed,
                                                        offsets, out, 0xFFFFFF, N);
    } else if (ws_size >= need_ids) {
        int* eids    = (int*)d_ws;
        int* counts  = eids + E;
        int* offsets = counts + N;
        int* cursors = offsets + N + 1;
        int* bsums   = cursors + N;

        hipMemsetAsync(counts, 0, sizeof(int) * (size_t)N, stream);
        hist_kernel<<<egrid, 256, 0, stream>>>(dst, counts, E);
        block_sum_kernel<<<nb, SCAN_BLOCK, 0, stream>>>(counts, bsums, N);
        scan_bsums_kernel<<<1, 64, 0, stream>>>(bsums, nb);
        scan_final_kernel<<<nb, SCAN_BLOCK, 0, stream>>>(counts, bsums, offsets, cursors, N, E);
        scatter_ids_kernel<<<egrid, 256, 0, stream>>>(dst, cursors, eids, E);
        accum_ids_kernel<<<N, US, 0, stream>>>(x, sh, src, offsets, eids, out);
    } else {
        hipMemsetAsync(out, 0, sizeof(float) * (size_t)out_size, stream);
        atomic_kernel<<<E, US, 0, stream>>>(x, sh, src, dst, out, E);
    }
}